// Round 2
// baseline (5108.858 us; speedup 1.0000x reference)
//
#include <hip/hip_runtime.h>

#define Ecnt 120000
#define Ncnt 15000
#define Tcnt 500000

// LDS layout helper: element (k, r) of a transposed tile lives at
// 68*k + (r ^ (((k>>3)&7)<<2)).  XOR keeps 4-row float4 chunks contiguous and
// 16B-aligned while spreading banks across k within a wave (rule #21: applied
// on BOTH write and read sides).
__device__ __forceinline__ int swz(int k, int r) {
    return k * 68 + (r ^ (((k >> 3) & 7) << 2));
}

// ---------------- small kernels ----------------

__launch_bounds__(256)
__global__ void sentinel_k(float* o, float v) { o[0] = v; }

__launch_bounds__(256)
__global__ void atype_k(const float* __restrict__ af, int* __restrict__ atype) {
    int n = blockIdx.x * 256 + threadIdx.x;
    if (n >= Ncnt) return;
    const float* r = af + (size_t)n * 133;
    int best = 0; float bv = r[0];
    for (int k = 1; k < 100; ++k) { float v = r[k]; if (v > bv) { bv = v; best = k; } }
    atype[n] = best;
}

// P1 = emb @ W[0:128], P2 = emb @ W[128:256]  (100x128 each)
__launch_bounds__(128)
__global__ void pemb_k(const float* __restrict__ emb, const float* __restrict__ W,
                       float* __restrict__ P1, float* __restrict__ P2) {
    int r = blockIdx.x, c = threadIdx.x;
    __shared__ float er[128];
    er[c] = emb[r * 128 + c];
    __syncthreads();
    float a1 = 0.f, a2 = 0.f;
    for (int k = 0; k < 128; ++k) {
        float e = er[k];
        a1 = fmaf(e, W[k * 128 + c], a1);
        a2 = fmaf(e, W[(128 + k) * 128 + c], a2);
    }
    P1[r * 128 + c] = a1;
    P2[r * 128 + c] = a2;
}

__launch_bounds__(256)
__global__ void rbf0_k(const float* __restrict__ dist, const float* __restrict__ freq,
                       float* __restrict__ rbf0) {
    int e = blockIdx.x * 256 + threadIdx.x;
    if (e >= Ecnt) return;
    float x = dist[e] * 0.125f;
    float x2 = x * x;
    float x5 = x2 * x2 * x;
    float env = 1.f / x - 28.f * x5 + 48.f * x5 * x - 21.f * x5 * x2;
    if (!(x < 1.f)) env = 0.f;
    #pragma unroll
    for (int r = 0; r < 16; ++r)
        rbf0[(size_t)e * 16 + r] = env * sinf(freq[r] * x);
}

// rbf_h = relu(rbf0 @ lin_rbf_w + b)   K=16
__launch_bounds__(256)
__global__ void rbfh_k(const float* __restrict__ rbf0, const float* __restrict__ W,
                       const float* __restrict__ bias, float* __restrict__ Y) {
    int gid = blockIdx.x * 256 + threadIdx.x;
    int e = gid >> 7, c = gid & 127;
    float acc = bias[c];
    #pragma unroll
    for (int k = 0; k < 16; ++k)
        acc = fmaf(rbf0[(size_t)e * 16 + k], W[k * 128 + c], acc);
    Y[(size_t)e * 128 + c] = fmaxf(acc, 0.f);
}

// msg += A + C
__launch_bounds__(256)
__global__ void addmsg_k(float* __restrict__ msg, const float* __restrict__ A,
                         const float* __restrict__ C) {
    size_t i = (size_t)blockIdx.x * 256 + threadIdx.x;
    float4 m = ((const float4*)msg)[i];
    float4 a = ((const float4*)A)[i];
    float4 c = ((const float4*)C)[i];
    m.x += a.x + c.x; m.y += a.y + c.y; m.z += a.z + c.z; m.w += a.w + c.w;
    ((float4*)msg)[i] = m;
}

__launch_bounds__(256)
__global__ void scatatom_k(const float* __restrict__ msg, const int* __restrict__ eid,
                           const int* __restrict__ aid, float* __restrict__ am) {
    int gid = blockIdx.x * 256 + threadIdx.x;
    int e = gid >> 7, c = gid & 127;
    float v = msg[(size_t)eid[e] * 128 + c];
    atomicAdd(&am[(size_t)aid[e] * 128 + c], v);
}

// ---------------- K=128 GEMM: Y = relu(X1 @ W + b [+P1/P2]) [* Xm] ----------------
// 64-row tile; X staged transposed+swizzled in LDS via float4 global loads.
// In-place (Y == X1) is safe: block reads only its own 64 rows (fully staged
// before the barrier) and writes only those rows afterwards.
template<bool MULTOUT, bool ADD2>
__launch_bounds__(256)
__global__ void gemm128_k(const float* X1, const float* Xm,
                          const float* __restrict__ W, const float* __restrict__ bias,
                          float* Y, int M,
                          const int* __restrict__ ei, const int* __restrict__ ej,
                          const int* __restrict__ atype,
                          const float* __restrict__ P1, const float* __restrict__ P2) {
    __shared__ float xs[128 * 68];
    const int tid = threadIdx.x;
    const int row0 = blockIdx.x * 64;

    #pragma unroll
    for (int it = 0; it < 8; ++it) {
        int chunk = tid + it * 256;          // 0..2047
        int kk = chunk & 127, rg = chunk >> 7;  // rg 0..15
        float v[4];
        #pragma unroll
        for (int i = 0; i < 4; ++i) {
            int row = row0 + rg * 4 + i;
            v[i] = (row < M) ? X1[(size_t)row * 128 + kk] : 0.f;
        }
        *(float4*)&xs[swz(kk, rg * 4)] = make_float4(v[0], v[1], v[2], v[3]);
    }
    __syncthreads();

    const int col8 = (tid & 15) * 8;
    const int r0 = (tid >> 4) * 4;
    float acc[4][8];
    #pragma unroll
    for (int r = 0; r < 4; ++r)
        #pragma unroll
        for (int c = 0; c < 8; ++c) acc[r][c] = 0.f;

    #pragma unroll 4
    for (int k = 0; k < 128; ++k) {
        float4 xv = *(const float4*)&xs[swz(k, r0)];
        const float* wr = &W[(size_t)k * 128 + col8];
        float4 w0 = *(const float4*)wr;
        float4 w1 = *(const float4*)(wr + 4);
        float xr[4] = {xv.x, xv.y, xv.z, xv.w};
        float wc[8] = {w0.x, w0.y, w0.z, w0.w, w1.x, w1.y, w1.z, w1.w};
        #pragma unroll
        for (int r = 0; r < 4; ++r)
            #pragma unroll
            for (int c = 0; c < 8; ++c)
                acc[r][c] = fmaf(xr[r], wc[c], acc[r][c]);
    }

    float4 b0 = *(const float4*)&bias[col8];
    float4 b1 = *(const float4*)&bias[col8 + 4];
    float bb[8] = {b0.x, b0.y, b0.z, b0.w, b1.x, b1.y, b1.z, b1.w};

    #pragma unroll
    for (int r = 0; r < 4; ++r) {
        int row = row0 + r0 + r;
        if (row >= M) continue;
        float v[8];
        #pragma unroll
        for (int c = 0; c < 8; ++c) v[c] = acc[r][c] + bb[c];
        if (ADD2) {
            int t1 = atype[ei[row]] * 128 + col8;
            int t2 = atype[ej[row]] * 128 + col8;
            float4 p10 = *(const float4*)&P1[t1]; float4 p11 = *(const float4*)&P1[t1 + 4];
            float4 p20 = *(const float4*)&P2[t2]; float4 p21 = *(const float4*)&P2[t2 + 4];
            v[0] += p10.x + p20.x; v[1] += p10.y + p20.y; v[2] += p10.z + p20.z; v[3] += p10.w + p20.w;
            v[4] += p11.x + p21.x; v[5] += p11.y + p21.y; v[6] += p11.z + p21.z; v[7] += p11.w + p21.w;
        }
        #pragma unroll
        for (int c = 0; c < 8; ++c) v[c] = fmaxf(v[c], 0.f);
        if (MULTOUT) {
            float4 m0 = *(const float4*)&Xm[(size_t)row * 128 + col8];
            float4 m1 = *(const float4*)&Xm[(size_t)row * 128 + col8 + 4];
            v[0] *= m0.x; v[1] *= m0.y; v[2] *= m0.z; v[3] *= m0.w;
            v[4] *= m1.x; v[5] *= m1.y; v[6] *= m1.z; v[7] *= m1.w;
        }
        *(float4*)&Y[(size_t)row * 128 + col8]     = make_float4(v[0], v[1], v[2], v[3]);
        *(float4*)&Y[(size_t)row * 128 + col8 + 4] = make_float4(v[4], v[5], v[6], v[7]);
    }
}

// ---------------- concat GEMM: out = relu(concat(IN1[g], IN2[row]) @ W + b) ----------------
template<bool GATHER>
__launch_bounds__(256)
__global__ void concatgemm_k(const float* __restrict__ IN1, int K1,
                             const float* __restrict__ IN2, int K2,
                             const int* __restrict__ gidx,
                             const float* __restrict__ W, const float* __restrict__ bias,
                             float* __restrict__ Y, int M) {
    __shared__ float xs[96 * 68];
    const int tid = threadIdx.x;
    const int row0 = blockIdx.x * 64;
    const int col8 = (tid & 15) * 8;
    const int r0 = (tid >> 4) * 4;
    const int K = K1 + K2;

    float acc[4][8];
    #pragma unroll
    for (int r = 0; r < 4; ++r)
        #pragma unroll
        for (int c = 0; c < 8; ++c) acc[r][c] = 0.f;

    for (int kb = 0; kb < K; kb += 96) {
        int kc = (K - kb < 96) ? (K - kb) : 96;
        __syncthreads();
        for (int idx = tid; idx < 64 * 96; idx += 256) {
            int r = idx / 96, kl = idx % 96;
            if (kl < kc) {
                int row = row0 + r;
                float v = 0.f;
                if (row < M) {
                    int kg = kb + kl;
                    if (kg < K1) {
                        int g = GATHER ? gidx[row] : row;
                        v = IN1[(size_t)g * K1 + kg];
                    } else {
                        v = IN2[(size_t)row * K2 + (kg - K1)];
                    }
                }
                xs[kl * 68 + r] = v;
            }
        }
        __syncthreads();
        for (int k = 0; k < kc; ++k) {
            float4 xv = *(const float4*)&xs[k * 68 + r0];
            const float* wr = &W[(size_t)(kb + k) * 128 + col8];
            float4 w0 = *(const float4*)wr;
            float4 w1 = *(const float4*)(wr + 4);
            float xr[4] = {xv.x, xv.y, xv.z, xv.w};
            float wc[8] = {w0.x, w0.y, w0.z, w0.w, w1.x, w1.y, w1.z, w1.w};
            #pragma unroll
            for (int r = 0; r < 4; ++r)
                #pragma unroll
                for (int c = 0; c < 8; ++c)
                    acc[r][c] = fmaf(xr[r], wc[c], acc[r][c]);
        }
    }

    float4 b0 = *(const float4*)&bias[col8];
    float4 b1 = *(const float4*)&bias[col8 + 4];
    float bb[8] = {b0.x, b0.y, b0.z, b0.w, b1.x, b1.y, b1.z, b1.w};
    #pragma unroll
    for (int r = 0; r < 4; ++r) {
        int row = row0 + r0 + r;
        if (row >= M) continue;
        float v[8];
        #pragma unroll
        for (int c = 0; c < 8; ++c) v[c] = fmaxf(acc[r][c] + bb[c], 0.f);
        *(float4*)&Y[(size_t)row * 128 + col8]     = make_float4(v[0], v[1], v[2], v[3]);
        *(float4*)&Y[(size_t)row * 128 + col8 + 4] = make_float4(v[4], v[5], v[6], v[7]);
    }
}

// ---------------- fused triplet path ----------------
// Per 64-row T-tile: build sbf in LDS -> s1 = relu(sbf@sbf1W) (K=96)
// -> s2 = relu(s1@sbf2W) (K=128) -> x = xdown[idx_kj]*s2
// -> y = relu(x@upW + b) (K=128) -> atomicAdd into agg[idx_kj].
__launch_bounds__(256)
__global__ void triplet_k(const float* __restrict__ angle, const int* __restrict__ idx_kj,
                          const float* __restrict__ rbf0,
                          const float* __restrict__ sbf1W, const float* __restrict__ sbf2W,
                          const float* __restrict__ upW, const float* __restrict__ upB,
                          const float* __restrict__ xdown, float* __restrict__ agg) {
    __shared__ float xs[128 * 68];
    const int tid = threadIdx.x;
    const int row0 = blockIdx.x * 64;
    const int col8 = (tid & 15) * 8;
    const int r0 = (tid >> 4) * 4;

    // stage sbf [96 x 64] (linear layout; writes are conflict-free: r varies per lane)
    if (tid < 128) {
        int r = tid & 63, half = tid >> 6;
        int row = row0 + r;
        float cb[3], rb[16];
        if (row < Tcnt) {
            float ang = angle[row];
            #pragma unroll
            for (int a = 0; a < 3; ++a) cb[a] = cosf(ang * (float)(half * 3 + a));
            int g = idx_kj[row];
            #pragma unroll
            for (int q = 0; q < 16; ++q) rb[q] = rbf0[(size_t)g * 16 + q];
        } else {
            #pragma unroll
            for (int a = 0; a < 3; ++a) cb[a] = 0.f;
            #pragma unroll
            for (int q = 0; q < 16; ++q) rb[q] = 0.f;
        }
        #pragma unroll
        for (int a = 0; a < 3; ++a)
            #pragma unroll
            for (int q = 0; q < 16; ++q)
                xs[((half * 3 + a) * 16 + q) * 68 + r] = cb[a] * rb[q];
    }

    // cache this thread's 4 triplet indices
    int g4[4];
    #pragma unroll
    for (int r = 0; r < 4; ++r) {
        int row = row0 + r0 + r;
        g4[r] = (row < Tcnt) ? idx_kj[row] : -1;
    }
    __syncthreads();

    float acc[4][8];

    // ---- GEMM1: s1 = relu(sbf @ sbf1W), K=96 (linear reads) ----
    #pragma unroll
    for (int r = 0; r < 4; ++r)
        #pragma unroll
        for (int c = 0; c < 8; ++c) acc[r][c] = 0.f;
    #pragma unroll 4
    for (int k = 0; k < 96; ++k) {
        float4 xv = *(const float4*)&xs[k * 68 + r0];
        const float* wr = &sbf1W[(size_t)k * 128 + col8];
        float4 w0 = *(const float4*)wr;
        float4 w1 = *(const float4*)(wr + 4);
        float xr[4] = {xv.x, xv.y, xv.z, xv.w};
        float wc[8] = {w0.x, w0.y, w0.z, w0.w, w1.x, w1.y, w1.z, w1.w};
        #pragma unroll
        for (int r = 0; r < 4; ++r)
            #pragma unroll
            for (int c = 0; c < 8; ++c)
                acc[r][c] = fmaf(xr[r], wc[c], acc[r][c]);
    }
    __syncthreads();
    // write s1 transposed+swizzled (float4 along rows)
    #pragma unroll
    for (int c = 0; c < 8; ++c) {
        float4 v = make_float4(fmaxf(acc[0][c], 0.f), fmaxf(acc[1][c], 0.f),
                               fmaxf(acc[2][c], 0.f), fmaxf(acc[3][c], 0.f));
        *(float4*)&xs[swz(col8 + c, r0)] = v;
    }
    __syncthreads();

    // ---- GEMM2: s2 = relu(s1 @ sbf2W), K=128 (swizzled reads) ----
    #pragma unroll
    for (int r = 0; r < 4; ++r)
        #pragma unroll
        for (int c = 0; c < 8; ++c) acc[r][c] = 0.f;
    #pragma unroll 4
    for (int k = 0; k < 128; ++k) {
        float4 xv = *(const float4*)&xs[swz(k, r0)];
        const float* wr = &sbf2W[(size_t)k * 128 + col8];
        float4 w0 = *(const float4*)wr;
        float4 w1 = *(const float4*)(wr + 4);
        float xr[4] = {xv.x, xv.y, xv.z, xv.w};
        float wc[8] = {w0.x, w0.y, w0.z, w0.w, w1.x, w1.y, w1.z, w1.w};
        #pragma unroll
        for (int r = 0; r < 4; ++r)
            #pragma unroll
            for (int c = 0; c < 8; ++c)
                acc[r][c] = fmaf(xr[r], wc[c], acc[r][c]);
    }
    __syncthreads();
    // gather xdown rows, multiply, write transposed+swizzled
    float xd[4][8];
    #pragma unroll
    for (int r = 0; r < 4; ++r) {
        if (g4[r] >= 0) {
            const float* dp = &xdown[(size_t)g4[r] * 128 + col8];
            float4 d0 = *(const float4*)dp;
            float4 d1 = *(const float4*)(dp + 4);
            xd[r][0] = d0.x; xd[r][1] = d0.y; xd[r][2] = d0.z; xd[r][3] = d0.w;
            xd[r][4] = d1.x; xd[r][5] = d1.y; xd[r][6] = d1.z; xd[r][7] = d1.w;
        } else {
            #pragma unroll
            for (int c = 0; c < 8; ++c) xd[r][c] = 0.f;
        }
    }
    #pragma unroll
    for (int c = 0; c < 8; ++c) {
        float4 v = make_float4(fmaxf(acc[0][c], 0.f) * xd[0][c],
                               fmaxf(acc[1][c], 0.f) * xd[1][c],
                               fmaxf(acc[2][c], 0.f) * xd[2][c],
                               fmaxf(acc[3][c], 0.f) * xd[3][c]);
        *(float4*)&xs[swz(col8 + c, r0)] = v;
    }
    __syncthreads();

    // ---- GEMM3: y = relu(x @ upW + b), K=128, scatter ----
    #pragma unroll
    for (int r = 0; r < 4; ++r)
        #pragma unroll
        for (int c = 0; c < 8; ++c) acc[r][c] = 0.f;
    #pragma unroll 4
    for (int k = 0; k < 128; ++k) {
        float4 xv = *(const float4*)&xs[swz(k, r0)];
        const float* wr = &upW[(size_t)k * 128 + col8];
        float4 w0 = *(const float4*)wr;
        float4 w1 = *(const float4*)(wr + 4);
        float xr[4] = {xv.x, xv.y, xv.z, xv.w};
        float wc[8] = {w0.x, w0.y, w0.z, w0.w, w1.x, w1.y, w1.z, w1.w};
        #pragma unroll
        for (int r = 0; r < 4; ++r)
            #pragma unroll
            for (int c = 0; c < 8; ++c)
                acc[r][c] = fmaf(xr[r], wc[c], acc[r][c]);
    }
    float4 b0 = *(const float4*)&upB[col8];
    float4 b1 = *(const float4*)&upB[col8 + 4];
    float bb[8] = {b0.x, b0.y, b0.z, b0.w, b1.x, b1.y, b1.z, b1.w};
    #pragma unroll
    for (int r = 0; r < 4; ++r) {
        if (g4[r] < 0) continue;
        float* yp = &agg[(size_t)g4[r] * 128 + col8];
        #pragma unroll
        for (int c = 0; c < 8; ++c)
            atomicAdd(yp + c, fmaxf(acc[r][c] + bb[c], 0.f));
    }
}

// ---------------- host ----------------

extern "C" void kernel_launch(void* const* d_in, const int* in_sizes, int n_in,
                              void* d_out, int out_size, void* d_ws, size_t ws_size,
                              hipStream_t stream) {
    const float* atom_feature = (const float*)d_in[0];
    const float* edge_feature = (const float*)d_in[1];
    const float* dist         = (const float*)d_in[2];
    const float* angle        = (const float*)d_in[3];
    const float* W_i1_w       = (const float*)d_in[4];
    const float* W_i1_b       = (const float*)d_in[5];
    const float* emb_table    = (const float*)d_in[6];
    const float* lin_rbf_w    = (const float*)d_in[7];
    const float* lin_rbf_b    = (const float*)d_in[8];
    const float* lin_emb_w    = (const float*)d_in[9];
    const float* lin_emb_b    = (const float*)d_in[10];
    const float* bessel_freq  = (const float*)d_in[11];
    const float* L_rbf2_w     = (const float*)d_in[12];
    const float* L_rbf2_b     = (const float*)d_in[13];
    const float* L_kj_w       = (const float*)d_in[14];
    const float* L_kj_b       = (const float*)d_in[15];
    const float* L_sbf1_w     = (const float*)d_in[16];
    const float* L_sbf2_w     = (const float*)d_in[17];
    const float* L_down_w     = (const float*)d_in[18];
    const float* L_down_b     = (const float*)d_in[19];
    const float* L_up_w       = (const float*)d_in[20];
    const float* L_up_b       = (const float*)d_in[21];
    const float* L_res1_w     = (const float*)d_in[22];
    const float* L_res1_b     = (const float*)d_in[23];
    const float* L_res2_w     = (const float*)d_in[24];
    const float* L_res2_b     = (const float*)d_in[25];
    const float* W_o_w        = (const float*)d_in[26];
    const float* W_o_b        = (const float*)d_in[27];
    const int* idx_i          = (const int*)d_in[28];
    const int* idx_j          = (const int*)d_in[29];
    const int* idx_kj         = (const int*)d_in[30];
    const int* ib_eid         = (const int*)d_in[32];
    const int* ib_atom        = (const int*)d_in[33];

    float* ws = (float*)d_ws;
    size_t off = 0;
    auto take = [&](size_t n) { float* p = ws + off; off += n; return p; };
    float* msg   = take((size_t)Ecnt * 128);
    float* rbfe  = take((size_t)Ecnt * 128);
    float* bufA  = take((size_t)Ecnt * 128);
    float* bufB  = take((size_t)Ecnt * 128);
    float* rbf0b = take((size_t)Ecnt * 16);
    float* atomm = take((size_t)Ncnt * 128);
    float* P1    = take(100 * 128);
    float* P2    = take(100 * 128);
    int*   atyp  = (int*)take(Ncnt);

    if (off * sizeof(float) > ws_size) {
        sentinel_k<<<1, 256, 0, stream>>>((float*)d_out, (float)ws_size);
        return;
    }

    const int GE = Ecnt / 64;             // 1875 (exact)
    const int GN = (Ncnt + 63) / 64;      // 235
    const int GT = (Tcnt + 63) / 64;      // 7813

    atype_k<<<(Ncnt + 255) / 256, 256, 0, stream>>>(atom_feature, atyp);
    pemb_k<<<100, 128, 0, stream>>>(emb_table, lin_emb_w, P1, P2);
    rbf0_k<<<(Ecnt + 255) / 256, 256, 0, stream>>>(dist, bessel_freq, rbf0b);

    // initial message = relu(concat(atom_feature[j], edge_feature) @ W_i1 + b)
    concatgemm_k<true><<<GE, 256, 0, stream>>>(atom_feature, 133, edge_feature, 14,
                                               idx_j, W_i1_w, W_i1_b, msg, Ecnt);

    // rbf_h -> bufA; rbf_e = relu(P1[t[i]] + P2[t[j]] + rbf_h @ W3 + b) -> rbfe
    rbfh_k<<<(Ecnt * 128) / 256, 256, 0, stream>>>(rbf0b, lin_rbf_w, lin_rbf_b, bufA);
    gemm128_k<false, true><<<GE, 256, 0, stream>>>(
        bufA, nullptr, lin_emb_w + 256 * 128, lin_emb_b, rbfe, Ecnt,
        idx_i, idx_j, atyp, P1, P2);

    for (int l = 0; l < 2; ++l) {
        const float* kjW   = L_kj_w   + (size_t)l * 128 * 128;
        const float* kjB   = L_kj_b   + (size_t)l * 128;
        const float* rbf2W = L_rbf2_w + (size_t)l * 128 * 128;
        const float* rbf2B = L_rbf2_b + (size_t)l * 128;
        const float* downW = L_down_w + (size_t)l * 128 * 128;
        const float* downB = L_down_b + (size_t)l * 128;
        const float* sbf1W = L_sbf1_w + (size_t)l * 96 * 128;
        const float* sbf2W = L_sbf2_w + (size_t)l * 128 * 128;
        const float* upW   = L_up_w   + (size_t)l * 128 * 128;
        const float* upB   = L_up_b   + (size_t)l * 128;
        const float* r1W   = L_res1_w + (size_t)l * 128 * 128;
        const float* r1B   = L_res1_b + (size_t)l * 128;
        const float* r2W   = L_res2_w + (size_t)l * 128 * 128;
        const float* r2B   = L_res2_b + (size_t)l * 128;

        // r = relu(rbfe@rbf2W+b) -> bufB;  x_kj = relu(msg@kjW+b) * r -> bufA
        gemm128_k<false, false><<<GE, 256, 0, stream>>>(
            rbfe, nullptr, rbf2W, rbf2B, bufB, Ecnt, nullptr, nullptr, nullptr, nullptr, nullptr);
        gemm128_k<true, false><<<GE, 256, 0, stream>>>(
            msg, bufB, kjW, kjB, bufA, Ecnt, nullptr, nullptr, nullptr, nullptr, nullptr);
        // x_down = relu(x_kj@downW+b) in-place -> bufA
        gemm128_k<false, false><<<GE, 256, 0, stream>>>(
            bufA, nullptr, downW, downB, bufA, Ecnt, nullptr, nullptr, nullptr, nullptr, nullptr);

        // agg = scatter(relu(up(x_down[idx_kj] * s2))) -> bufB
        hipMemsetAsync(bufB, 0, (size_t)Ecnt * 128 * sizeof(float), stream);
        triplet_k<<<GT, 256, 0, stream>>>(angle, idx_kj, rbf0b, sbf1W, sbf2W,
                                          upW, upB, bufA, bufB);

        // res chain: bufA = relu(bufB@r1+b); bufA = relu(bufA@r2+b) in-place
        gemm128_k<false, false><<<GE, 256, 0, stream>>>(
            bufB, nullptr, r1W, r1B, bufA, Ecnt, nullptr, nullptr, nullptr, nullptr, nullptr);
        gemm128_k<false, false><<<GE, 256, 0, stream>>>(
            bufA, nullptr, r2W, r2B, bufA, Ecnt, nullptr, nullptr, nullptr, nullptr, nullptr);
        // msg = x_ji + agg + res
        addmsg_k<<<(Ecnt * 128 / 4) / 256, 256, 0, stream>>>(msg, bufB, bufA);
    }

    // atom_message scatter + final projection
    hipMemsetAsync(atomm, 0, (size_t)Ncnt * 128 * sizeof(float), stream);
    scatatom_k<<<(Ecnt * 128) / 256, 256, 0, stream>>>(msg, ib_eid, ib_atom, atomm);
    concatgemm_k<false><<<GN, 256, 0, stream>>>(atom_feature, 133, atomm, 128,
                                                nullptr, W_o_w, W_o_b, (float*)d_out, Ncnt);
}

// Round 3
// 2040.744 us; speedup vs baseline: 2.5034x; 2.5034x over previous
//
#include <hip/hip_runtime.h>
#include <hip/hip_bf16.h>

#define Ecnt 120000
#define Ncnt 15000
#define Tcnt 500000

typedef __attribute__((ext_vector_type(8))) short short8;
typedef __attribute__((ext_vector_type(4))) float floatx4;

__device__ __forceinline__ floatx4 mfma16(short8 a, short8 b, floatx4 c) {
    return __builtin_amdgcn_mfma_f32_16x16x32_bf16(a, b, c, 0, 0, 0);
}

__device__ __forceinline__ short f2bf(float f) {
    __hip_bfloat16 b = __float2bfloat16(f);
    short s;
    __builtin_memcpy(&s, &b, 2);
    return s;
}

// fp32-GEMM LDS swizzle (unchanged, round-2-verified)
__device__ __forceinline__ int swz(int k, int r) {
    return k * 68 + (r ^ (((k >> 3) & 7) << 2));
}

// bf16 MFMA tile swizzle: row-major [64][256B], byte-col XOR (row&15)<<4.
// Bijective within the 256B row; applied on BOTH write and read (rule #21).
__device__ __forceinline__ int sidx(int row, int bc) {
    return row * 128 + (((bc) ^ ((row & 15) << 4)) >> 1);   // short index
}

// ---------------- small kernels ----------------

__launch_bounds__(256)
__global__ void sentinel_k(float* o, float v) { o[0] = v; }

__launch_bounds__(256)
__global__ void atype_k(const float* __restrict__ af, int* __restrict__ atype) {
    int n = blockIdx.x * 256 + threadIdx.x;
    if (n >= Ncnt) return;
    const float* r = af + (size_t)n * 133;
    int best = 0; float bv = r[0];
    for (int k = 1; k < 100; ++k) { float v = r[k]; if (v > bv) { bv = v; best = k; } }
    atype[n] = best;
}

__launch_bounds__(128)
__global__ void pemb_k(const float* __restrict__ emb, const float* __restrict__ W,
                       float* __restrict__ P1, float* __restrict__ P2) {
    int r = blockIdx.x, c = threadIdx.x;
    __shared__ float er[128];
    er[c] = emb[r * 128 + c];
    __syncthreads();
    float a1 = 0.f, a2 = 0.f;
    for (int k = 0; k < 128; ++k) {
        float e = er[k];
        a1 = fmaf(e, W[k * 128 + c], a1);
        a2 = fmaf(e, W[(128 + k) * 128 + c], a2);
    }
    P1[r * 128 + c] = a1;
    P2[r * 128 + c] = a2;
}

__launch_bounds__(256)
__global__ void rbf0_k(const float* __restrict__ dist, const float* __restrict__ freq,
                       float* __restrict__ rbf0) {
    int e = blockIdx.x * 256 + threadIdx.x;
    if (e >= Ecnt) return;
    float x = dist[e] * 0.125f;
    float x2 = x * x;
    float x5 = x2 * x2 * x;
    float env = 1.f / x - 28.f * x5 + 48.f * x5 * x - 21.f * x5 * x2;
    if (!(x < 1.f)) env = 0.f;
    #pragma unroll
    for (int r = 0; r < 16; ++r)
        rbf0[(size_t)e * 16 + r] = env * sinf(freq[r] * x);
}

__launch_bounds__(256)
__global__ void rbfh_k(const float* __restrict__ rbf0, const float* __restrict__ W,
                       const float* __restrict__ bias, float* __restrict__ Y) {
    int gid = blockIdx.x * 256 + threadIdx.x;
    int e = gid >> 7, c = gid & 127;
    float acc = bias[c];
    #pragma unroll
    for (int k = 0; k < 16; ++k)
        acc = fmaf(rbf0[(size_t)e * 16 + k], W[k * 128 + c], acc);
    Y[(size_t)e * 128 + c] = fmaxf(acc, 0.f);
}

__launch_bounds__(256)
__global__ void addmsg_k(float* __restrict__ msg, const float* __restrict__ A,
                         const float* __restrict__ C) {
    size_t i = (size_t)blockIdx.x * 256 + threadIdx.x;
    float4 m = ((const float4*)msg)[i];
    float4 a = ((const float4*)A)[i];
    float4 c = ((const float4*)C)[i];
    m.x += a.x + c.x; m.y += a.y + c.y; m.z += a.z + c.z; m.w += a.w + c.w;
    ((float4*)msg)[i] = m;
}

__launch_bounds__(256)
__global__ void scatatom_k(const float* __restrict__ msg, const int* __restrict__ eid,
                           const int* __restrict__ aid, float* __restrict__ am) {
    int gid = blockIdx.x * 256 + threadIdx.x;
    int e = gid >> 7, c = gid & 127;
    float v = msg[(size_t)eid[e] * 128 + c];
    atomicAdd(&am[(size_t)aid[e] * 128 + c], v);
}

// ---------------- sorting (perm such that idx_kj[perm] is sorted) ----------------

__launch_bounds__(256)
__global__ void hist_k(const int* __restrict__ idx, int* __restrict__ cnt) {
    int t = blockIdx.x * 256 + threadIdx.x;
    if (t < Tcnt) atomicAdd(&cnt[idx[t]], 1);
}

// per-block (256) exclusive scan of cnt -> basep, block total -> btot
__launch_bounds__(256)
__global__ void scan1_k(const int* __restrict__ cnt, int* __restrict__ basep,
                        int* __restrict__ btot) {
    __shared__ int s[256];
    int t = threadIdx.x, i = blockIdx.x * 256 + t;
    int v = (i < Ecnt) ? cnt[i] : 0;
    s[t] = v;
    #pragma unroll
    for (int off = 1; off < 256; off <<= 1) {
        __syncthreads();
        int nv = (t >= off) ? s[t - off] + s[t] : s[t];
        __syncthreads();
        s[t] = nv;
    }
    if (i < Ecnt) basep[i] = s[t] - v;
    if (t == 255) btot[blockIdx.x] = s[255];
}

// single block: exclusive scan of btot (nb <= 512) -> boff
__launch_bounds__(512)
__global__ void scan2_k(const int* __restrict__ btot, int* __restrict__ boff, int nb) {
    __shared__ int s[512];
    int t = threadIdx.x;
    int v = (t < nb) ? btot[t] : 0;
    s[t] = v;
    #pragma unroll
    for (int off = 1; off < 512; off <<= 1) {
        __syncthreads();
        int nv = (t >= off) ? s[t - off] + s[t] : s[t];
        __syncthreads();
        s[t] = nv;
    }
    if (t < nb) boff[t] = s[t] - v;
}

__launch_bounds__(256)
__global__ void scan3_k(const int* __restrict__ basep, const int* __restrict__ boff,
                        int* __restrict__ cur) {
    int i = blockIdx.x * 256 + threadIdx.x;
    if (i < Ecnt) cur[i] = basep[i] + boff[i >> 8];
}

__launch_bounds__(256)
__global__ void perm_k(const int* __restrict__ idx, int* __restrict__ cur,
                       int* __restrict__ perm) {
    int t = blockIdx.x * 256 + threadIdx.x;
    if (t >= Tcnt) return;
    int e = idx[t];
    int p = atomicAdd(&cur[e], 1);
    perm[p] = t;
}

// transpose+convert weight: W [K][128] f32 -> out [128][K] bf16
__launch_bounds__(256)
__global__ void transcvt_k(const float* __restrict__ W, short* __restrict__ out, int K) {
    int i = blockIdx.x * 256 + threadIdx.x;
    if (i >= K * 128) return;
    int k = i >> 7, c = i & 127;
    out[c * K + k] = f2bf(W[k * 128 + c]);
}

// ---------------- fused triplet path, bf16 MFMA, sorted ----------------
// Per 64-sorted-row tile: build sbf bf16 in ldsA -> s1=relu(sbf@W1) (K=96)
// -> s2=relu(s1@W2)*xdown[e] (K=128) -> y=relu(x@W3+b) -> merged atomics to agg[e].
// Waves own disjoint 16-row groups; weights (pre-transposed bf16) stream from L1/L2.
__launch_bounds__(256)
__global__ void triplet_mfma_k(const float* __restrict__ angle, const int* __restrict__ idx_kj,
                               const int* __restrict__ perm, const float* __restrict__ rbf0,
                               const short* __restrict__ W1t, const short* __restrict__ W2t,
                               const short* __restrict__ W3t, const float* __restrict__ upB,
                               const float* __restrict__ xdown, float* __restrict__ agg) {
    __shared__ short ldsA[64 * 128];   // 16 KB  (sbf, then s2*xd)
    __shared__ short ldsB[64 * 128];   // 16 KB  (s1)
    const int tid = threadIdx.x;
    const int lane = tid & 63;
    const int w = tid >> 6;
    const int row0 = blockIdx.x * 64;

    // ---- stage sbf [64 rows][96 bf16] into ldsA (each thread: 1 quarter-row) ----
    {
        int r = tid & 63, q = tid >> 6;
        int srow = row0 + r;
        int tt = (srow < Tcnt) ? perm[srow] : -1;
        float cb[6], rb[16];
        if (tt >= 0) {
            float ang = angle[tt];
            int ge = idx_kj[tt];
            #pragma unroll
            for (int a = 0; a < 6; ++a) cb[a] = cosf(ang * (float)a);
            #pragma unroll
            for (int i4 = 0; i4 < 4; ++i4) {
                float4 r4 = *(const float4*)&rbf0[(size_t)ge * 16 + i4 * 4];
                rb[i4*4+0] = r4.x; rb[i4*4+1] = r4.y; rb[i4*4+2] = r4.z; rb[i4*4+3] = r4.w;
            }
        } else {
            #pragma unroll
            for (int a = 0; a < 6; ++a) cb[a] = 0.f;
            #pragma unroll
            for (int qq = 0; qq < 16; ++qq) rb[qq] = 0.f;
        }
        #pragma unroll
        for (int m = 0; m < 12; ++m) {
            int v0 = q * 24 + 2 * m;
            float f0 = cb[v0 >> 4] * rb[v0 & 15];
            float f1 = cb[(v0 + 1) >> 4] * rb[(v0 + 1) & 15];
            unsigned u = (unsigned)(unsigned short)f2bf(f0) |
                         ((unsigned)(unsigned short)f2bf(f1) << 16);
            *(unsigned*)&ldsA[sidx(r, 4 * (q * 12 + m))] = u;
        }
    }

    // per-lane constants
    const int kgrp = lane >> 4;               // 0..3
    const int arow = w * 16 + (lane & 15);    // A-frag row (tile-local)
    const int cr0  = w * 16 + kgrp * 4;       // first C row (tile-local)
    const int ccol = lane & 15;               // C col within 16-tile
    int eid[4];
    #pragma unroll
    for (int j = 0; j < 4; ++j) {
        int sr = row0 + cr0 + j;
        eid[j] = (sr < Tcnt) ? idx_kj[perm[sr]] : -1;
    }

    // prefetch xdown gather (T14: issue early, consume after GEMM2)
    float xd[8][4];
    #pragma unroll
    for (int c = 0; c < 8; ++c)
        #pragma unroll
        for (int j = 0; j < 4; ++j)
            xd[c][j] = (eid[j] >= 0) ? xdown[(size_t)eid[j] * 128 + c * 16 + ccol] : 0.f;

    __syncthreads();

    // ---- GEMM1: s1 = relu(sbf @ W1), K=96 ----
    {
        short8 a0 = *(const short8*)&ldsA[sidx(arow, 0   + kgrp * 16)];
        short8 a1 = *(const short8*)&ldsA[sidx(arow, 64  + kgrp * 16)];
        short8 a2 = *(const short8*)&ldsA[sidx(arow, 128 + kgrp * 16)];
        #pragma unroll
        for (int c = 0; c < 8; ++c) {
            const short* wp = W1t + (size_t)(c * 16 + ccol) * 96 + kgrp * 8;
            short8 b0 = *(const short8*)(wp);
            short8 b1 = *(const short8*)(wp + 32);
            short8 b2 = *(const short8*)(wp + 64);
            floatx4 acc = {0.f, 0.f, 0.f, 0.f};
            acc = mfma16(a0, b0, acc);
            acc = mfma16(a1, b1, acc);
            acc = mfma16(a2, b2, acc);
            #pragma unroll
            for (int j = 0; j < 4; ++j)
                ldsB[sidx(cr0 + j, 2 * (c * 16 + ccol))] = f2bf(fmaxf(acc[j], 0.f));
        }
    }
    __syncthreads();

    // ---- GEMM2: s2 = relu(s1 @ W2) * xd, K=128 ----
    {
        short8 a[4];
        #pragma unroll
        for (int kb = 0; kb < 4; ++kb)
            a[kb] = *(const short8*)&ldsB[sidx(arow, kb * 64 + kgrp * 16)];
        #pragma unroll
        for (int c = 0; c < 8; ++c) {
            const short* wp = W2t + (size_t)(c * 16 + ccol) * 128 + kgrp * 8;
            floatx4 acc = {0.f, 0.f, 0.f, 0.f};
            #pragma unroll
            for (int kb = 0; kb < 4; ++kb)
                acc = mfma16(a[kb], *(const short8*)(wp + kb * 32), acc);
            #pragma unroll
            for (int j = 0; j < 4; ++j) {
                float v = fmaxf(acc[j], 0.f) * xd[c][j];
                ldsA[sidx(cr0 + j, 2 * (c * 16 + ccol))] = f2bf(v);
            }
        }
    }
    __syncthreads();

    // ---- GEMM3: y = relu(x @ W3 + b), merged atomic scatter ----
    {
        short8 a[4];
        #pragma unroll
        for (int kb = 0; kb < 4; ++kb)
            a[kb] = *(const short8*)&ldsA[sidx(arow, kb * 64 + kgrp * 16)];
        float bv[8];
        #pragma unroll
        for (int c = 0; c < 8; ++c) bv[c] = upB[c * 16 + ccol];
        #pragma unroll
        for (int c = 0; c < 8; ++c) {
            const short* wp = W3t + (size_t)(c * 16 + ccol) * 128 + kgrp * 8;
            floatx4 acc = {0.f, 0.f, 0.f, 0.f};
            #pragma unroll
            for (int kb = 0; kb < 4; ++kb)
                acc = mfma16(a[kb], *(const short8*)(wp + kb * 32), acc);
            float v0 = fmaxf(acc[0] + bv[c], 0.f);
            float v1 = fmaxf(acc[1] + bv[c], 0.f);
            float v2 = fmaxf(acc[2] + bv[c], 0.f);
            float v3 = fmaxf(acc[3] + bv[c], 0.f);
            int col = c * 16 + ccol;
            // sorted rows: merge duplicates in-register before atomics
            if (eid[0] == eid[1]) v1 += v0;
            else if (eid[0] >= 0) atomicAdd(&agg[(size_t)eid[0] * 128 + col], v0);
            if (eid[1] == eid[2]) v2 += v1;
            else if (eid[1] >= 0) atomicAdd(&agg[(size_t)eid[1] * 128 + col], v1);
            if (eid[2] == eid[3]) v3 += v2;
            else if (eid[2] >= 0) atomicAdd(&agg[(size_t)eid[2] * 128 + col], v2);
            if (eid[3] >= 0) atomicAdd(&agg[(size_t)eid[3] * 128 + col], v3);
        }
    }
}

// ---------------- fp32 K=128 GEMM (E-path, unchanged from round 2) ----------------
template<bool MULTOUT, bool ADD2>
__launch_bounds__(256)
__global__ void gemm128_k(const float* X1, const float* Xm,
                          const float* __restrict__ W, const float* __restrict__ bias,
                          float* Y, int M,
                          const int* __restrict__ ei, const int* __restrict__ ej,
                          const int* __restrict__ atype,
                          const float* __restrict__ P1, const float* __restrict__ P2) {
    __shared__ float xs[128 * 68];
    const int tid = threadIdx.x;
    const int row0 = blockIdx.x * 64;

    #pragma unroll
    for (int it = 0; it < 8; ++it) {
        int chunk = tid + it * 256;
        int kk = chunk & 127, rg = chunk >> 7;
        float v[4];
        #pragma unroll
        for (int i = 0; i < 4; ++i) {
            int row = row0 + rg * 4 + i;
            v[i] = (row < M) ? X1[(size_t)row * 128 + kk] : 0.f;
        }
        *(float4*)&xs[swz(kk, rg * 4)] = make_float4(v[0], v[1], v[2], v[3]);
    }
    __syncthreads();

    const int col8 = (tid & 15) * 8;
    const int r0 = (tid >> 4) * 4;
    float acc[4][8];
    #pragma unroll
    for (int r = 0; r < 4; ++r)
        #pragma unroll
        for (int c = 0; c < 8; ++c) acc[r][c] = 0.f;

    #pragma unroll 4
    for (int k = 0; k < 128; ++k) {
        float4 xv = *(const float4*)&xs[swz(k, r0)];
        const float* wr = &W[(size_t)k * 128 + col8];
        float4 w0 = *(const float4*)wr;
        float4 w1 = *(const float4*)(wr + 4);
        float xr[4] = {xv.x, xv.y, xv.z, xv.w};
        float wc[8] = {w0.x, w0.y, w0.z, w0.w, w1.x, w1.y, w1.z, w1.w};
        #pragma unroll
        for (int r = 0; r < 4; ++r)
            #pragma unroll
            for (int c = 0; c < 8; ++c)
                acc[r][c] = fmaf(xr[r], wc[c], acc[r][c]);
    }

    float4 b0 = *(const float4*)&bias[col8];
    float4 b1 = *(const float4*)&bias[col8 + 4];
    float bb[8] = {b0.x, b0.y, b0.z, b0.w, b1.x, b1.y, b1.z, b1.w};

    #pragma unroll
    for (int r = 0; r < 4; ++r) {
        int row = row0 + r0 + r;
        if (row >= M) continue;
        float v[8];
        #pragma unroll
        for (int c = 0; c < 8; ++c) v[c] = acc[r][c] + bb[c];
        if (ADD2) {
            int t1 = atype[ei[row]] * 128 + col8;
            int t2 = atype[ej[row]] * 128 + col8;
            float4 p10 = *(const float4*)&P1[t1]; float4 p11 = *(const float4*)&P1[t1 + 4];
            float4 p20 = *(const float4*)&P2[t2]; float4 p21 = *(const float4*)&P2[t2 + 4];
            v[0] += p10.x + p20.x; v[1] += p10.y + p20.y; v[2] += p10.z + p20.z; v[3] += p10.w + p20.w;
            v[4] += p11.x + p21.x; v[5] += p11.y + p21.y; v[6] += p11.z + p21.z; v[7] += p11.w + p21.w;
        }
        #pragma unroll
        for (int c = 0; c < 8; ++c) v[c] = fmaxf(v[c], 0.f);
        if (MULTOUT) {
            float4 m0 = *(const float4*)&Xm[(size_t)row * 128 + col8];
            float4 m1 = *(const float4*)&Xm[(size_t)row * 128 + col8 + 4];
            v[0] *= m0.x; v[1] *= m0.y; v[2] *= m0.z; v[3] *= m0.w;
            v[4] *= m1.x; v[5] *= m1.y; v[6] *= m1.z; v[7] *= m1.w;
        }
        *(float4*)&Y[(size_t)row * 128 + col8]     = make_float4(v[0], v[1], v[2], v[3]);
        *(float4*)&Y[(size_t)row * 128 + col8 + 4] = make_float4(v[4], v[5], v[6], v[7]);
    }
}

// ---------------- concat GEMM (unchanged) ----------------
template<bool GATHER>
__launch_bounds__(256)
__global__ void concatgemm_k(const float* __restrict__ IN1, int K1,
                             const float* __restrict__ IN2, int K2,
                             const int* __restrict__ gidx,
                             const float* __restrict__ W, const float* __restrict__ bias,
                             float* __restrict__ Y, int M) {
    __shared__ float xs[96 * 68];
    const int tid = threadIdx.x;
    const int row0 = blockIdx.x * 64;
    const int col8 = (tid & 15) * 8;
    const int r0 = (tid >> 4) * 4;
    const int K = K1 + K2;

    float acc[4][8];
    #pragma unroll
    for (int r = 0; r < 4; ++r)
        #pragma unroll
        for (int c = 0; c < 8; ++c) acc[r][c] = 0.f;

    for (int kb = 0; kb < K; kb += 96) {
        int kc = (K - kb < 96) ? (K - kb) : 96;
        __syncthreads();
        for (int idx = tid; idx < 64 * 96; idx += 256) {
            int r = idx / 96, kl = idx % 96;
            if (kl < kc) {
                int row = row0 + r;
                float v = 0.f;
                if (row < M) {
                    int kg = kb + kl;
                    if (kg < K1) {
                        int g = GATHER ? gidx[row] : row;
                        v = IN1[(size_t)g * K1 + kg];
                    } else {
                        v = IN2[(size_t)row * K2 + (kg - K1)];
                    }
                }
                xs[kl * 68 + r] = v;
            }
        }
        __syncthreads();
        for (int k = 0; k < kc; ++k) {
            float4 xv = *(const float4*)&xs[k * 68 + r0];
            const float* wr = &W[(size_t)(kb + k) * 128 + col8];
            float4 w0 = *(const float4*)wr;
            float4 w1 = *(const float4*)(wr + 4);
            float xr[4] = {xv.x, xv.y, xv.z, xv.w};
            float wc[8] = {w0.x, w0.y, w0.z, w0.w, w1.x, w1.y, w1.z, w1.w};
            #pragma unroll
            for (int r = 0; r < 4; ++r)
                #pragma unroll
                for (int c = 0; c < 8; ++c)
                    acc[r][c] = fmaf(xr[r], wc[c], acc[r][c]);
        }
    }

    float4 b0 = *(const float4*)&bias[col8];
    float4 b1 = *(const float4*)&bias[col8 + 4];
    float bb[8] = {b0.x, b0.y, b0.z, b0.w, b1.x, b1.y, b1.z, b1.w};
    #pragma unroll
    for (int r = 0; r < 4; ++r) {
        int row = row0 + r0 + r;
        if (row >= M) continue;
        float v[8];
        #pragma unroll
        for (int c = 0; c < 8; ++c) v[c] = fmaxf(acc[r][c] + bb[c], 0.f);
        *(float4*)&Y[(size_t)row * 128 + col8]     = make_float4(v[0], v[1], v[2], v[3]);
        *(float4*)&Y[(size_t)row * 128 + col8 + 4] = make_float4(v[4], v[5], v[6], v[7]);
    }
}

// ---------------- host ----------------

extern "C" void kernel_launch(void* const* d_in, const int* in_sizes, int n_in,
                              void* d_out, int out_size, void* d_ws, size_t ws_size,
                              hipStream_t stream) {
    const float* atom_feature = (const float*)d_in[0];
    const float* edge_feature = (const float*)d_in[1];
    const float* dist         = (const float*)d_in[2];
    const float* angle        = (const float*)d_in[3];
    const float* W_i1_w       = (const float*)d_in[4];
    const float* W_i1_b       = (const float*)d_in[5];
    const float* emb_table    = (const float*)d_in[6];
    const float* lin_rbf_w    = (const float*)d_in[7];
    const float* lin_rbf_b    = (const float*)d_in[8];
    const float* lin_emb_w    = (const float*)d_in[9];
    const float* lin_emb_b    = (const float*)d_in[10];
    const float* bessel_freq  = (const float*)d_in[11];
    const float* L_rbf2_w     = (const float*)d_in[12];
    const float* L_rbf2_b     = (const float*)d_in[13];
    const float* L_kj_w       = (const float*)d_in[14];
    const float* L_kj_b       = (const float*)d_in[15];
    const float* L_sbf1_w     = (const float*)d_in[16];
    const float* L_sbf2_w     = (const float*)d_in[17];
    const float* L_down_w     = (const float*)d_in[18];
    const float* L_down_b     = (const float*)d_in[19];
    const float* L_up_w       = (const float*)d_in[20];
    const float* L_up_b       = (const float*)d_in[21];
    const float* L_res1_w     = (const float*)d_in[22];
    const float* L_res1_b     = (const float*)d_in[23];
    const float* L_res2_w     = (const float*)d_in[24];
    const float* L_res2_b     = (const float*)d_in[25];
    const float* W_o_w        = (const float*)d_in[26];
    const float* W_o_b        = (const float*)d_in[27];
    const int* idx_i          = (const int*)d_in[28];
    const int* idx_j          = (const int*)d_in[29];
    const int* idx_kj         = (const int*)d_in[30];
    const int* ib_eid         = (const int*)d_in[32];
    const int* ib_atom        = (const int*)d_in[33];

    float* ws = (float*)d_ws;
    size_t off = 0;
    auto take = [&](size_t n) { float* p = ws + off; off += n; return p; };
    float* msg   = take((size_t)Ecnt * 128);
    float* rbfe  = take((size_t)Ecnt * 128);
    float* bufA  = take((size_t)Ecnt * 128);
    float* bufB  = take((size_t)Ecnt * 128);
    float* rbf0b = take((size_t)Ecnt * 16);
    float* atomm = take((size_t)Ncnt * 128);
    float* P1    = take(100 * 128);
    float* P2    = take(100 * 128);
    int*   atyp  = (int*)take(Ncnt);
    int*   cnts  = (int*)take(Ecnt);
    int*   basep = (int*)take(Ecnt);
    int*   cur   = (int*)take(Ecnt);
    int*   btot  = (int*)take(512);
    int*   boff  = (int*)take(512);
    int*   perm  = (int*)take(Tcnt);
    short* wts   = (short*)take(2 * (96 + 128 + 128) * 128 / 2 + 64);

    if (off * sizeof(float) > ws_size) {
        sentinel_k<<<1, 256, 0, stream>>>((float*)d_out, (float)ws_size);
        return;
    }

    const int GE = Ecnt / 64;             // 1875 (exact)
    const int GN = (Ncnt + 63) / 64;      // 235
    const int GT = (Tcnt + 63) / 64;      // 7813
    const int NBE = (Ecnt + 255) / 256;   // 469
    const int NBT = (Tcnt + 255) / 256;   // 1954

    // --- prep: atype / P-tables / rbf0 ---
    atype_k<<<(Ncnt + 255) / 256, 256, 0, stream>>>(atom_feature, atyp);
    pemb_k<<<100, 128, 0, stream>>>(emb_table, lin_emb_w, P1, P2);
    rbf0_k<<<NBE, 256, 0, stream>>>(dist, bessel_freq, rbf0b);

    // --- prep: sort triplets by target edge ---
    hipMemsetAsync(cnts, 0, (size_t)Ecnt * sizeof(int), stream);
    hist_k<<<NBT, 256, 0, stream>>>(idx_kj, cnts);
    scan1_k<<<NBE, 256, 0, stream>>>(cnts, basep, btot);
    scan2_k<<<1, 512, 0, stream>>>(btot, boff, NBE);
    scan3_k<<<NBE, 256, 0, stream>>>(basep, boff, cur);
    perm_k<<<NBT, 256, 0, stream>>>(idx_kj, cur, perm);

    // --- prep: bf16-transposed triplet weights ---
    short* wt1[2]; short* wt2[2]; short* wt3[2];
    {
        short* p = wts;
        for (int l = 0; l < 2; ++l) {
            wt1[l] = p; p += 96 * 128;
            wt2[l] = p; p += 128 * 128;
            wt3[l] = p; p += 128 * 128;
        }
        for (int l = 0; l < 2; ++l) {
            transcvt_k<<<(96 * 128 + 255) / 256, 256, 0, stream>>>(
                L_sbf1_w + (size_t)l * 96 * 128, wt1[l], 96);
            transcvt_k<<<(128 * 128 + 255) / 256, 256, 0, stream>>>(
                L_sbf2_w + (size_t)l * 128 * 128, wt2[l], 128);
            transcvt_k<<<(128 * 128 + 255) / 256, 256, 0, stream>>>(
                L_up_w + (size_t)l * 128 * 128, wt3[l], 128);
        }
    }

    // --- initial message + rbf_e ---
    concatgemm_k<true><<<GE, 256, 0, stream>>>(atom_feature, 133, edge_feature, 14,
                                               idx_j, W_i1_w, W_i1_b, msg, Ecnt);
    rbfh_k<<<(Ecnt * 128) / 256, 256, 0, stream>>>(rbf0b, lin_rbf_w, lin_rbf_b, bufA);
    gemm128_k<false, true><<<GE, 256, 0, stream>>>(
        bufA, nullptr, lin_emb_w + 256 * 128, lin_emb_b, rbfe, Ecnt,
        idx_i, idx_j, atyp, P1, P2);

    for (int l = 0; l < 2; ++l) {
        const float* kjW   = L_kj_w   + (size_t)l * 128 * 128;
        const float* kjB   = L_kj_b   + (size_t)l * 128;
        const float* rbf2W = L_rbf2_w + (size_t)l * 128 * 128;
        const float* rbf2B = L_rbf2_b + (size_t)l * 128;
        const float* downW = L_down_w + (size_t)l * 128 * 128;
        const float* downB = L_down_b + (size_t)l * 128;
        const float* upB   = L_up_b   + (size_t)l * 128;
        const float* r1W   = L_res1_w + (size_t)l * 128 * 128;
        const float* r1B   = L_res1_b + (size_t)l * 128;
        const float* r2W   = L_res2_w + (size_t)l * 128 * 128;
        const float* r2B   = L_res2_b + (size_t)l * 128;

        // r = relu(rbfe@rbf2W+b) -> bufB;  x_kj = relu(msg@kjW+b)*r -> bufA
        gemm128_k<false, false><<<GE, 256, 0, stream>>>(
            rbfe, nullptr, rbf2W, rbf2B, bufB, Ecnt, nullptr, nullptr, nullptr, nullptr, nullptr);
        gemm128_k<true, false><<<GE, 256, 0, stream>>>(
            msg, bufB, kjW, kjB, bufA, Ecnt, nullptr, nullptr, nullptr, nullptr, nullptr);
        // x_down = relu(x_kj@downW+b) in-place -> bufA
        gemm128_k<false, false><<<GE, 256, 0, stream>>>(
            bufA, nullptr, downW, downB, bufA, Ecnt, nullptr, nullptr, nullptr, nullptr, nullptr);

        // triplet path (sorted, MFMA, fused scatter) -> bufB
        hipMemsetAsync(bufB, 0, (size_t)Ecnt * 128 * sizeof(float), stream);
        triplet_mfma_k<<<GT, 256, 0, stream>>>(angle, idx_kj, perm, rbf0b,
                                               wt1[l], wt2[l], wt3[l], upB, bufA, bufB);

        // residual MLP, then msg = x_ji + agg + res
        gemm128_k<false, false><<<GE, 256, 0, stream>>>(
            bufB, nullptr, r1W, r1B, bufA, Ecnt, nullptr, nullptr, nullptr, nullptr, nullptr);
        gemm128_k<false, false><<<GE, 256, 0, stream>>>(
            bufA, nullptr, r2W, r2B, bufA, Ecnt, nullptr, nullptr, nullptr, nullptr, nullptr);
        addmsg_k<<<(Ecnt * 128 / 4) / 256, 256, 0, stream>>>(msg, bufB, bufA);
    }

    // atom_message scatter + final projection
    hipMemsetAsync(atomm, 0, (size_t)Ncnt * 128 * sizeof(float), stream);
    scatatom_k<<<(Ecnt * 128) / 256, 256, 0, stream>>>(msg, ib_eid, ib_atom, atomm);
    concatgemm_k<false><<<GN, 256, 0, stream>>>(atom_feature, 133, atomm, 128,
                                                nullptr, W_o_w, W_o_b, (float*)d_out, Ncnt);
}

// Round 4
// 1588.725 us; speedup vs baseline: 3.2157x; 1.2845x over previous
//
#include <hip/hip_runtime.h>
#include <hip/hip_bf16.h>

#define Ecnt 120000
#define Ncnt 15000
#define Tcnt 500000

typedef __attribute__((ext_vector_type(8))) short short8;
typedef __attribute__((ext_vector_type(4))) float floatx4;

__device__ __forceinline__ floatx4 mfma16(short8 a, short8 b, floatx4 c) {
    return __builtin_amdgcn_mfma_f32_16x16x32_bf16(a, b, c, 0, 0, 0);
}

__device__ __forceinline__ short f2bf(float f) {
    __hip_bfloat16 b = __float2bfloat16(f);
    short s;
    __builtin_memcpy(&s, &b, 2);
    return s;
}

__device__ __forceinline__ float bf2f(short s) {
    unsigned u = ((unsigned)(unsigned short)s) << 16;
    float f;
    __builtin_memcpy(&f, &u, 4);
    return f;
}

__device__ __forceinline__ unsigned pack2(float x, float y) {
    return (unsigned)(unsigned short)f2bf(x) | ((unsigned)(unsigned short)f2bf(y) << 16);
}

// fp32-GEMM LDS swizzle (concatgemm only)
__device__ __forceinline__ int swz(int k, int r) {
    return k * 68 + (r ^ (((k >> 3) & 7) << 2));
}

// bf16 MFMA tile: row-major [64][256B], byte-col XOR (row&15)<<4, both sides.
__device__ __forceinline__ int sidx(int row, int bc) {
    return row * 128 + (((bc) ^ ((row & 15) << 4)) >> 1);   // short index
}

// stage 64x128 f32 tile -> bf16 swizzled LDS (rows exact, no bounds)
__device__ __forceinline__ void stage64x128(const float* __restrict__ src, size_t row0,
                                            short* __restrict__ lds, int tid) {
    #pragma unroll
    for (int it = 0; it < 8; ++it) {
        int chunk = tid + it * 256;       // 0..2047
        int r = chunk >> 5, c4 = chunk & 31;
        float4 v = *(const float4*)&src[(row0 + r) * 128 + c4 * 4];
        *(uint2*)&lds[sidx(r, c4 * 8)] = make_uint2(pack2(v.x, v.y), pack2(v.z, v.w));
    }
}

// 16x16 col-tile matmul over K=128 with preloaded A frags
__device__ __forceinline__ floatx4 colmm(const short8 a[4], const short* __restrict__ wp) {
    floatx4 acc = {0.f, 0.f, 0.f, 0.f};
    #pragma unroll
    for (int kb = 0; kb < 4; ++kb)
        acc = mfma16(a[kb], *(const short8*)(wp + kb * 32), acc);
    return acc;
}

// ---------------- small kernels ----------------

__launch_bounds__(256)
__global__ void sentinel_k(float* o, float v) { o[0] = v; }

__launch_bounds__(256)
__global__ void atype_k(const float* __restrict__ af, int* __restrict__ atype) {
    int n = blockIdx.x * 256 + threadIdx.x;
    if (n >= Ncnt) return;
    const float* r = af + (size_t)n * 133;
    int best = 0; float bv = r[0];
    for (int k = 1; k < 100; ++k) { float v = r[k]; if (v > bv) { bv = v; best = k; } }
    atype[n] = best;
}

__launch_bounds__(128)
__global__ void pemb_k(const float* __restrict__ emb, const float* __restrict__ W,
                       float* __restrict__ P1, float* __restrict__ P2) {
    int r = blockIdx.x, c = threadIdx.x;
    __shared__ float er[128];
    er[c] = emb[r * 128 + c];
    __syncthreads();
    float a1 = 0.f, a2 = 0.f;
    for (int k = 0; k < 128; ++k) {
        float e = er[k];
        a1 = fmaf(e, W[k * 128 + c], a1);
        a2 = fmaf(e, W[(128 + k) * 128 + c], a2);
    }
    P1[r * 128 + c] = a1;
    P2[r * 128 + c] = a2;
}

__launch_bounds__(256)
__global__ void rbf0_k(const float* __restrict__ dist, const float* __restrict__ freq,
                       float* __restrict__ rbf0) {
    int e = blockIdx.x * 256 + threadIdx.x;
    if (e >= Ecnt) return;
    float x = dist[e] * 0.125f;
    float x2 = x * x;
    float x5 = x2 * x2 * x;
    float env = 1.f / x - 28.f * x5 + 48.f * x5 * x - 21.f * x5 * x2;
    if (!(x < 1.f)) env = 0.f;
    #pragma unroll
    for (int r = 0; r < 16; ++r)
        rbf0[(size_t)e * 16 + r] = env * sinf(freq[r] * x);
}

__launch_bounds__(256)
__global__ void rbfh_k(const float* __restrict__ rbf0, const float* __restrict__ W,
                       const float* __restrict__ bias, float* __restrict__ Y) {
    int gid = blockIdx.x * 256 + threadIdx.x;
    int e = gid >> 7, c = gid & 127;
    float acc = bias[c];
    #pragma unroll
    for (int k = 0; k < 16; ++k)
        acc = fmaf(rbf0[(size_t)e * 16 + k], W[k * 128 + c], acc);
    Y[(size_t)e * 128 + c] = fmaxf(acc, 0.f);
}

__launch_bounds__(256)
__global__ void scatatom_k(const float* __restrict__ msg, const int* __restrict__ eid,
                           const int* __restrict__ aid, float* __restrict__ am) {
    int gid = blockIdx.x * 256 + threadIdx.x;
    int e = gid >> 7, c = gid & 127;
    float v = msg[(size_t)eid[e] * 128 + c];
    atomicAdd(&am[(size_t)aid[e] * 128 + c], v);
}

// ---------------- sorting ----------------

__launch_bounds__(256)
__global__ void hist_k(const int* __restrict__ idx, int* __restrict__ cnt) {
    int t = blockIdx.x * 256 + threadIdx.x;
    if (t < Tcnt) atomicAdd(&cnt[idx[t]], 1);
}

__launch_bounds__(256)
__global__ void scan1_k(const int* __restrict__ cnt, int* __restrict__ basep,
                        int* __restrict__ btot) {
    __shared__ int s[256];
    int t = threadIdx.x, i = blockIdx.x * 256 + t;
    int v = (i < Ecnt) ? cnt[i] : 0;
    s[t] = v;
    #pragma unroll
    for (int off = 1; off < 256; off <<= 1) {
        __syncthreads();
        int nv = (t >= off) ? s[t - off] + s[t] : s[t];
        __syncthreads();
        s[t] = nv;
    }
    if (i < Ecnt) basep[i] = s[t] - v;
    if (t == 255) btot[blockIdx.x] = s[255];
}

__launch_bounds__(512)
__global__ void scan2_k(const int* __restrict__ btot, int* __restrict__ boff, int nb) {
    __shared__ int s[512];
    int t = threadIdx.x;
    int v = (t < nb) ? btot[t] : 0;
    s[t] = v;
    #pragma unroll
    for (int off = 1; off < 512; off <<= 1) {
        __syncthreads();
        int nv = (t >= off) ? s[t - off] + s[t] : s[t];
        __syncthreads();
        s[t] = nv;
    }
    if (t < nb) boff[t] = s[t] - v;
}

__launch_bounds__(256)
__global__ void scan3_k(const int* __restrict__ basep, const int* __restrict__ boff,
                        int* __restrict__ cur) {
    int i = blockIdx.x * 256 + threadIdx.x;
    if (i < Ecnt) cur[i] = basep[i] + boff[i >> 8];
}

// scatter triplet payload into sorted order: eids (target edge), angs (angle)
__launch_bounds__(256)
__global__ void perm_k(const int* __restrict__ idx, const float* __restrict__ angle,
                       int* __restrict__ cur, int* __restrict__ eids,
                       float* __restrict__ angs) {
    int t = blockIdx.x * 256 + threadIdx.x;
    if (t >= Tcnt) return;
    int e = idx[t];
    int p = atomicAdd(&cur[e], 1);
    eids[p] = e;
    angs[p] = angle[t];
}

// transpose+convert weight: W [K][128] f32 -> out [128][K] bf16
__launch_bounds__(256)
__global__ void transcvt_k(const float* __restrict__ W, short* __restrict__ out, int K) {
    int i = blockIdx.x * 256 + threadIdx.x;
    if (i >= K * 128) return;
    int k = i >> 7, c = i & 127;
    out[c * K + k] = f2bf(W[k * 128 + c]);
}

// ---------------- fused triplet path (bf16 MFMA, sorted) ----------------
__launch_bounds__(256)
__global__ void triplet_mfma_k(const float* __restrict__ angs, const int* __restrict__ eids,
                               const float* __restrict__ rbf0,
                               const short* __restrict__ W1t, const short* __restrict__ W2t,
                               const short* __restrict__ W3t, const float* __restrict__ upB,
                               const short* __restrict__ xdown, float* __restrict__ agg) {
    __shared__ short ldsA[64 * 128];
    __shared__ short ldsB[64 * 128];
    const int tid = threadIdx.x;
    const int lane = tid & 63;
    const int w = tid >> 6;
    const int row0 = blockIdx.x * 64;

    // ---- stage sbf [64][96] bf16 (cos via Chebyshev recurrence) ----
    {
        int r = tid & 63, q = tid >> 6;
        int srow = row0 + r;
        float cb[6], rb[16];
        if (srow < Tcnt) {
            float ang = angs[srow];
            int ge = eids[srow];
            float c1 = cosf(ang);
            cb[0] = 1.f; cb[1] = c1;
            #pragma unroll
            for (int a = 2; a < 6; ++a) cb[a] = 2.f * c1 * cb[a - 1] - cb[a - 2];
            #pragma unroll
            for (int i4 = 0; i4 < 4; ++i4) {
                float4 r4 = *(const float4*)&rbf0[(size_t)ge * 16 + i4 * 4];
                rb[i4*4+0] = r4.x; rb[i4*4+1] = r4.y; rb[i4*4+2] = r4.z; rb[i4*4+3] = r4.w;
            }
        } else {
            #pragma unroll
            for (int a = 0; a < 6; ++a) cb[a] = 0.f;
            #pragma unroll
            for (int qq = 0; qq < 16; ++qq) rb[qq] = 0.f;
        }
        #pragma unroll
        for (int m = 0; m < 12; ++m) {
            int v0 = q * 24 + 2 * m;
            float f0 = cb[v0 >> 4] * rb[v0 & 15];
            float f1 = cb[(v0 + 1) >> 4] * rb[(v0 + 1) & 15];
            *(unsigned*)&ldsA[sidx(r, 4 * (q * 12 + m))] = pack2(f0, f1);
        }
    }

    const int kgrp = lane >> 4;
    const int arow = w * 16 + (lane & 15);
    const int cr0  = w * 16 + kgrp * 4;
    const int ccol = lane & 15;
    int eid[4];
    #pragma unroll
    for (int j = 0; j < 4; ++j) {
        int sr = row0 + cr0 + j;
        eid[j] = (sr < Tcnt) ? eids[sr] : -1;
    }

    // prefetch xdown gather (bf16)
    float xd[8][4];
    #pragma unroll
    for (int c = 0; c < 8; ++c)
        #pragma unroll
        for (int j = 0; j < 4; ++j)
            xd[c][j] = (eid[j] >= 0) ? bf2f(xdown[(size_t)eid[j] * 128 + c * 16 + ccol]) : 0.f;

    __syncthreads();

    // ---- GEMM1: s1 = relu(sbf @ W1), K=96 ----
    {
        short8 a0 = *(const short8*)&ldsA[sidx(arow, 0   + kgrp * 16)];
        short8 a1 = *(const short8*)&ldsA[sidx(arow, 64  + kgrp * 16)];
        short8 a2 = *(const short8*)&ldsA[sidx(arow, 128 + kgrp * 16)];
        #pragma unroll
        for (int c = 0; c < 8; ++c) {
            const short* wp = W1t + (size_t)(c * 16 + ccol) * 96 + kgrp * 8;
            floatx4 acc = {0.f, 0.f, 0.f, 0.f};
            acc = mfma16(a0, *(const short8*)(wp),      acc);
            acc = mfma16(a1, *(const short8*)(wp + 32), acc);
            acc = mfma16(a2, *(const short8*)(wp + 64), acc);
            #pragma unroll
            for (int j = 0; j < 4; ++j)
                ldsB[sidx(cr0 + j, 2 * (c * 16 + ccol))] = f2bf(fmaxf(acc[j], 0.f));
        }
    }
    __syncthreads();

    // ---- GEMM2: s2 = relu(s1 @ W2) * xd, K=128 ----
    {
        short8 a[4];
        #pragma unroll
        for (int kb = 0; kb < 4; ++kb)
            a[kb] = *(const short8*)&ldsB[sidx(arow, kb * 64 + kgrp * 16)];
        #pragma unroll
        for (int c = 0; c < 8; ++c) {
            floatx4 acc = colmm(a, W2t + (size_t)(c * 16 + ccol) * 128 + kgrp * 8);
            #pragma unroll
            for (int j = 0; j < 4; ++j)
                ldsA[sidx(cr0 + j, 2 * (c * 16 + ccol))] = f2bf(fmaxf(acc[j], 0.f) * xd[c][j]);
        }
    }
    __syncthreads();

    // ---- GEMM3: y = relu(x @ W3 + b), merged atomic scatter ----
    {
        short8 a[4];
        #pragma unroll
        for (int kb = 0; kb < 4; ++kb)
            a[kb] = *(const short8*)&ldsA[sidx(arow, kb * 64 + kgrp * 16)];
        #pragma unroll
        for (int c = 0; c < 8; ++c) {
            int col = c * 16 + ccol;
            floatx4 acc = colmm(a, W3t + (size_t)col * 128 + kgrp * 8);
            float bv = upB[col];
            float v0 = fmaxf(acc[0] + bv, 0.f);
            float v1 = fmaxf(acc[1] + bv, 0.f);
            float v2 = fmaxf(acc[2] + bv, 0.f);
            float v3 = fmaxf(acc[3] + bv, 0.f);
            if (eid[0] == eid[1]) v1 += v0;
            else if (eid[0] >= 0) atomicAdd(&agg[(size_t)eid[0] * 128 + col], v0);
            if (eid[1] == eid[2]) v2 += v1;
            else if (eid[1] >= 0) atomicAdd(&agg[(size_t)eid[1] * 128 + col], v1);
            if (eid[2] == eid[3]) v3 += v2;
            else if (eid[2] >= 0) atomicAdd(&agg[(size_t)eid[2] * 128 + col], v2);
            if (eid[3] >= 0) atomicAdd(&agg[(size_t)eid[3] * 128 + col], v3);
        }
    }
}

// ---------------- layerA: xdown = relu((relu(msg@kjW+b) * relu(rbfe@rbf2W+b)) @ downW + b) ----------------
__launch_bounds__(256)
__global__ void layerA_k(const float* __restrict__ msg, const float* __restrict__ rbfe,
                         const short* __restrict__ kjWt, const float* __restrict__ kjB,
                         const short* __restrict__ rbf2Wt, const float* __restrict__ rbf2B,
                         const short* __restrict__ downWt, const float* __restrict__ downB,
                         short* __restrict__ xdown) {
    __shared__ short ldsM[64 * 128];
    __shared__ short ldsR[64 * 128];
    const int tid = threadIdx.x;
    const int lane = tid & 63, w = tid >> 6;
    const size_t row0 = (size_t)blockIdx.x * 64;
    stage64x128(msg,  row0, ldsM, tid);
    stage64x128(rbfe, row0, ldsR, tid);
    __syncthreads();
    const int kgrp = lane >> 4, ccol = lane & 15;
    const int arow = w * 16 + ccol;
    const int cr0  = w * 16 + kgrp * 4;
    short8 aM[4], aR[4];
    #pragma unroll
    for (int kb = 0; kb < 4; ++kb) {
        aM[kb] = *(const short8*)&ldsM[sidx(arow, kb * 64 + kgrp * 16)];
        aR[kb] = *(const short8*)&ldsR[sidx(arow, kb * 64 + kgrp * 16)];
    }
    #pragma unroll
    for (int c = 0; c < 8; ++c) {
        int colg = c * 16 + ccol;
        floatx4 ra = colmm(aR, rbf2Wt + (size_t)colg * 128 + kgrp * 8);
        floatx4 ka = colmm(aM, kjWt   + (size_t)colg * 128 + kgrp * 8);
        float rb = rbf2B[colg], kbb = kjB[colg];
        #pragma unroll
        for (int j = 0; j < 4; ++j) {
            float x = fmaxf(ka[j] + kbb, 0.f) * fmaxf(ra[j] + rb, 0.f);
            ldsM[sidx(cr0 + j, 2 * colg)] = f2bf(x);
        }
    }
    __syncthreads();
    short8 aX[4];
    #pragma unroll
    for (int kb = 0; kb < 4; ++kb)
        aX[kb] = *(const short8*)&ldsM[sidx(arow, kb * 64 + kgrp * 16)];
    #pragma unroll
    for (int c = 0; c < 8; ++c) {
        int colg = c * 16 + ccol;
        floatx4 acc = colmm(aX, downWt + (size_t)colg * 128 + kgrp * 8);
        float db = downB[colg];
        #pragma unroll
        for (int j = 0; j < 4; ++j)
            xdown[(row0 + cr0 + j) * 128 + colg] = f2bf(fmaxf(acc[j] + db, 0.f));
    }
}

// ---------------- layerB: msg += agg + relu(relu(agg@r1+b)@r2+b) ----------------
__launch_bounds__(256)
__global__ void layerB_k(const float* __restrict__ agg,
                         const short* __restrict__ r1Wt, const float* __restrict__ r1B,
                         const short* __restrict__ r2Wt, const float* __restrict__ r2B,
                         float* __restrict__ msg) {
    __shared__ short lds[64 * 128];
    const int tid = threadIdx.x;
    const int lane = tid & 63, w = tid >> 6;
    const size_t row0 = (size_t)blockIdx.x * 64;
    stage64x128(agg, row0, lds, tid);
    __syncthreads();
    const int kgrp = lane >> 4, ccol = lane & 15;
    const int arow = w * 16 + ccol;
    const int cr0  = w * 16 + kgrp * 4;
    short8 a1[4];
    #pragma unroll
    for (int kb = 0; kb < 4; ++kb)
        a1[kb] = *(const short8*)&lds[sidx(arow, kb * 64 + kgrp * 16)];
    #pragma unroll
    for (int c = 0; c < 8; ++c) {
        int colg = c * 16 + ccol;
        floatx4 acc = colmm(a1, r1Wt + (size_t)colg * 128 + kgrp * 8);
        float b1 = r1B[colg];
        #pragma unroll
        for (int j = 0; j < 4; ++j)
            lds[sidx(cr0 + j, 2 * colg)] = f2bf(fmaxf(acc[j] + b1, 0.f));
    }
    __syncthreads();
    short8 a2[4];
    #pragma unroll
    for (int kb = 0; kb < 4; ++kb)
        a2[kb] = *(const short8*)&lds[sidx(arow, kb * 64 + kgrp * 16)];
    #pragma unroll
    for (int c = 0; c < 8; ++c) {
        int colg = c * 16 + ccol;
        floatx4 acc = colmm(a2, r2Wt + (size_t)colg * 128 + kgrp * 8);
        float b2 = r2B[colg];
        #pragma unroll
        for (int j = 0; j < 4; ++j) {
            size_t o = (row0 + cr0 + j) * 128 + colg;
            msg[o] = msg[o] + agg[o] + fmaxf(acc[j] + b2, 0.f);
        }
    }
}

// ---------------- rbfe: relu(rbfh@W3 + b + P1[t(i)] + P2[t(j)]) ----------------
__launch_bounds__(256)
__global__ void rbfe_k(const float* __restrict__ rbfh, const short* __restrict__ W3t,
                       const float* __restrict__ bias,
                       const int* __restrict__ idx_i, const int* __restrict__ idx_j,
                       const int* __restrict__ atype,
                       const float* __restrict__ P1, const float* __restrict__ P2,
                       float* __restrict__ out) {
    __shared__ short lds[64 * 128];
    const int tid = threadIdx.x;
    const int lane = tid & 63, w = tid >> 6;
    const size_t row0 = (size_t)blockIdx.x * 64;
    stage64x128(rbfh, row0, lds, tid);
    const int kgrp = lane >> 4, ccol = lane & 15;
    const int arow = w * 16 + ccol;
    const int cr0  = w * 16 + kgrp * 4;
    const float* p1p[4]; const float* p2p[4];
    #pragma unroll
    for (int j = 0; j < 4; ++j) {
        size_t row = row0 + cr0 + j;
        p1p[j] = P1 + (size_t)atype[idx_i[row]] * 128;
        p2p[j] = P2 + (size_t)atype[idx_j[row]] * 128;
    }
    __syncthreads();
    short8 a[4];
    #pragma unroll
    for (int kb = 0; kb < 4; ++kb)
        a[kb] = *(const short8*)&lds[sidx(arow, kb * 64 + kgrp * 16)];
    #pragma unroll
    for (int c = 0; c < 8; ++c) {
        int colg = c * 16 + ccol;
        floatx4 acc = colmm(a, W3t + (size_t)colg * 128 + kgrp * 8);
        float bv = bias[colg];
        #pragma unroll
        for (int j = 0; j < 4; ++j)
            out[(row0 + cr0 + j) * 128 + colg] =
                fmaxf(acc[j] + bv + p1p[j][colg] + p2p[j][colg], 0.f);
    }
}

// ---------------- concat GEMM (fp32, initial message + final output) ----------------
template<bool GATHER>
__launch_bounds__(256)
__global__ void concatgemm_k(const float* __restrict__ IN1, int K1,
                             const float* __restrict__ IN2, int K2,
                             const int* __restrict__ gidx,
                             const float* __restrict__ W, const float* __restrict__ bias,
                             float* __restrict__ Y, int M) {
    __shared__ float xs[96 * 68];
    const int tid = threadIdx.x;
    const int row0 = blockIdx.x * 64;
    const int col8 = (tid & 15) * 8;
    const int r0 = (tid >> 4) * 4;
    const int K = K1 + K2;

    float acc[4][8];
    #pragma unroll
    for (int r = 0; r < 4; ++r)
        #pragma unroll
        for (int c = 0; c < 8; ++c) acc[r][c] = 0.f;

    for (int kb = 0; kb < K; kb += 96) {
        int kc = (K - kb < 96) ? (K - kb) : 96;
        __syncthreads();
        for (int idx = tid; idx < 64 * 96; idx += 256) {
            int r = idx / 96, kl = idx % 96;
            if (kl < kc) {
                int row = row0 + r;
                float v = 0.f;
                if (row < M) {
                    int kg = kb + kl;
                    if (kg < K1) {
                        int g = GATHER ? gidx[row] : row;
                        v = IN1[(size_t)g * K1 + kg];
                    } else {
                        v = IN2[(size_t)row * K2 + (kg - K1)];
                    }
                }
                xs[kl * 68 + r] = v;
            }
        }
        __syncthreads();
        for (int k = 0; k < kc; ++k) {
            float4 xv = *(const float4*)&xs[k * 68 + r0];
            const float* wr = &W[(size_t)(kb + k) * 128 + col8];
            float4 w0 = *(const float4*)wr;
            float4 w1 = *(const float4*)(wr + 4);
            float xr[4] = {xv.x, xv.y, xv.z, xv.w};
            float wc[8] = {w0.x, w0.y, w0.z, w0.w, w1.x, w1.y, w1.z, w1.w};
            #pragma unroll
            for (int r = 0; r < 4; ++r)
                #pragma unroll
                for (int c = 0; c < 8; ++c)
                    acc[r][c] = fmaf(xr[r], wc[c], acc[r][c]);
        }
    }

    float4 b0 = *(const float4*)&bias[col8];
    float4 b1 = *(const float4*)&bias[col8 + 4];
    float bb[8] = {b0.x, b0.y, b0.z, b0.w, b1.x, b1.y, b1.z, b1.w};
    #pragma unroll
    for (int r = 0; r < 4; ++r) {
        int row = row0 + r0 + r;
        if (row >= M) continue;
        float v[8];
        #pragma unroll
        for (int c = 0; c < 8; ++c) v[c] = fmaxf(acc[r][c] + bb[c], 0.f);
        *(float4*)&Y[(size_t)row * 128 + col8]     = make_float4(v[0], v[1], v[2], v[3]);
        *(float4*)&Y[(size_t)row * 128 + col8 + 4] = make_float4(v[4], v[5], v[6], v[7]);
    }
}

// ---------------- host ----------------

extern "C" void kernel_launch(void* const* d_in, const int* in_sizes, int n_in,
                              void* d_out, int out_size, void* d_ws, size_t ws_size,
                              hipStream_t stream) {
    const float* atom_feature = (const float*)d_in[0];
    const float* edge_feature = (const float*)d_in[1];
    const float* dist         = (const float*)d_in[2];
    const float* angle        = (const float*)d_in[3];
    const float* W_i1_w       = (const float*)d_in[4];
    const float* W_i1_b       = (const float*)d_in[5];
    const float* emb_table    = (const float*)d_in[6];
    const float* lin_rbf_w    = (const float*)d_in[7];
    const float* lin_rbf_b    = (const float*)d_in[8];
    const float* lin_emb_w    = (const float*)d_in[9];
    const float* lin_emb_b    = (const float*)d_in[10];
    const float* bessel_freq  = (const float*)d_in[11];
    const float* L_rbf2_w     = (const float*)d_in[12];
    const float* L_rbf2_b     = (const float*)d_in[13];
    const float* L_kj_w       = (const float*)d_in[14];
    const float* L_kj_b       = (const float*)d_in[15];
    const float* L_sbf1_w     = (const float*)d_in[16];
    const float* L_sbf2_w     = (const float*)d_in[17];
    const float* L_down_w     = (const float*)d_in[18];
    const float* L_down_b     = (const float*)d_in[19];
    const float* L_up_w       = (const float*)d_in[20];
    const float* L_up_b       = (const float*)d_in[21];
    const float* L_res1_w     = (const float*)d_in[22];
    const float* L_res1_b     = (const float*)d_in[23];
    const float* L_res2_w     = (const float*)d_in[24];
    const float* L_res2_b     = (const float*)d_in[25];
    const float* W_o_w        = (const float*)d_in[26];
    const float* W_o_b        = (const float*)d_in[27];
    const int* idx_i          = (const int*)d_in[28];
    const int* idx_j          = (const int*)d_in[29];
    const int* idx_kj         = (const int*)d_in[30];
    const int* ib_eid         = (const int*)d_in[32];
    const int* ib_atom        = (const int*)d_in[33];

    float* ws = (float*)d_ws;
    size_t off = 0;
    auto take = [&](size_t n) { float* p = ws + off; off += n; return p; };
    float* msg   = take((size_t)Ecnt * 128);
    float* rbfe  = take((size_t)Ecnt * 128);
    float* agg   = take((size_t)Ecnt * 128);   // also rbf_h temp before layers
    short* sxd   = (short*)take((size_t)Ecnt * 64);   // bf16 xdown
    float* rbf0b = take((size_t)Ecnt * 16);
    float* atomm = take((size_t)Ncnt * 128);
    float* P1    = take(100 * 128);
    float* P2    = take(100 * 128);
    int*   atyp  = (int*)take(Ncnt);
    int*   cnts  = (int*)take(Ecnt);
    int*   basep = (int*)take(Ecnt);
    int*   cur   = (int*)take(Ecnt);
    int*   btot  = (int*)take(512);
    int*   boff  = (int*)take(512);
    int*   eids  = (int*)take(Tcnt);
    float* angs  = take(Tcnt);
    short* wts   = (short*)take((2 * (96 + 128 + 128) * 128 + 11 * 128 * 128) / 2 + 64);

    if (off * sizeof(float) > ws_size) {
        sentinel_k<<<1, 256, 0, stream>>>((float*)d_out, (float)ws_size);
        return;
    }

    const int GE  = Ecnt / 64;            // 1875 exact
    const int GN  = (Ncnt + 63) / 64;     // 235
    const int GT  = (Tcnt + 63) / 64;     // 7813
    const int NBE = (Ecnt + 255) / 256;
    const int NBT = (Tcnt + 255) / 256;

    // --- prep ---
    atype_k<<<(Ncnt + 255) / 256, 256, 0, stream>>>(atom_feature, atyp);
    pemb_k<<<100, 128, 0, stream>>>(emb_table, lin_emb_w, P1, P2);
    rbf0_k<<<NBE, 256, 0, stream>>>(dist, bessel_freq, rbf0b);

    hipMemsetAsync(cnts, 0, (size_t)Ecnt * sizeof(int), stream);
    hist_k<<<NBT, 256, 0, stream>>>(idx_kj, cnts);
    scan1_k<<<NBE, 256, 0, stream>>>(cnts, basep, btot);
    scan2_k<<<1, 512, 0, stream>>>(btot, boff, NBE);
    scan3_k<<<NBE, 256, 0, stream>>>(basep, boff, cur);
    perm_k<<<NBT, 256, 0, stream>>>(idx_kj, angle, cur, eids, angs);

    // --- bf16 transposed weights ---
    short* wt1[2]; short* wt2[2]; short* wt3[2];
    short* wkj[2]; short* wr2f[2]; short* wdn[2]; short* wr1[2]; short* wr2[2];
    short* wemb3;
    {
        short* p = wts;
        for (int l = 0; l < 2; ++l) {
            wt1[l] = p; p += 96 * 128;
            wt2[l] = p; p += 128 * 128;
            wt3[l] = p; p += 128 * 128;
            wkj[l] = p; p += 128 * 128;
            wr2f[l] = p; p += 128 * 128;
            wdn[l] = p; p += 128 * 128;
            wr1[l] = p; p += 128 * 128;
            wr2[l] = p; p += 128 * 128;
        }
        wemb3 = p;
        const int G96 = (96 * 128 + 255) / 256, G128 = (128 * 128 + 255) / 256;
        for (int l = 0; l < 2; ++l) {
            transcvt_k<<<G96, 256, 0, stream>>>(L_sbf1_w + (size_t)l * 96 * 128, wt1[l], 96);
            transcvt_k<<<G128, 256, 0, stream>>>(L_sbf2_w + (size_t)l * 128 * 128, wt2[l], 128);
            transcvt_k<<<G128, 256, 0, stream>>>(L_up_w   + (size_t)l * 128 * 128, wt3[l], 128);
            transcvt_k<<<G128, 256, 0, stream>>>(L_kj_w   + (size_t)l * 128 * 128, wkj[l], 128);
            transcvt_k<<<G128, 256, 0, stream>>>(L_rbf2_w + (size_t)l * 128 * 128, wr2f[l], 128);
            transcvt_k<<<G128, 256, 0, stream>>>(L_down_w + (size_t)l * 128 * 128, wdn[l], 128);
            transcvt_k<<<G128, 256, 0, stream>>>(L_res1_w + (size_t)l * 128 * 128, wr1[l], 128);
            transcvt_k<<<G128, 256, 0, stream>>>(L_res2_w + (size_t)l * 128 * 128, wr2[l], 128);
        }
        transcvt_k<<<G128, 256, 0, stream>>>(lin_emb_w + 256 * 128, wemb3, 128);
    }

    // --- initial message + rbf_e ---
    concatgemm_k<true><<<GE, 256, 0, stream>>>(atom_feature, 133, edge_feature, 14,
                                               idx_j, W_i1_w, W_i1_b, msg, Ecnt);
    rbfh_k<<<(Ecnt * 128) / 256, 256, 0, stream>>>(rbf0b, lin_rbf_w, lin_rbf_b, agg);
    rbfe_k<<<GE, 256, 0, stream>>>(agg, wemb3, lin_emb_b, idx_i, idx_j, atyp, P1, P2, rbfe);

    for (int l = 0; l < 2; ++l) {
        layerA_k<<<GE, 256, 0, stream>>>(msg, rbfe,
                                         wkj[l], L_kj_b + (size_t)l * 128,
                                         wr2f[l], L_rbf2_b + (size_t)l * 128,
                                         wdn[l], L_down_b + (size_t)l * 128, sxd);
        hipMemsetAsync(agg, 0, (size_t)Ecnt * 128 * sizeof(float), stream);
        triplet_mfma_k<<<GT, 256, 0, stream>>>(angs, eids, rbf0b,
                                               wt1[l], wt2[l], wt3[l],
                                               L_up_b + (size_t)l * 128, sxd, agg);
        layerB_k<<<GE, 256, 0, stream>>>(agg,
                                         wr1[l], L_res1_b + (size_t)l * 128,
                                         wr2[l], L_res2_b + (size_t)l * 128, msg);
    }

    // atom_message scatter + final projection
    hipMemsetAsync(atomm, 0, (size_t)Ncnt * 128 * sizeof(float), stream);
    scatatom_k<<<(Ecnt * 128) / 256, 256, 0, stream>>>(msg, ib_eid, ib_atom, atomm);
    concatgemm_k<false><<<GN, 256, 0, stream>>>(atom_feature, 133, atomm, 128,
                                                nullptr, W_o_w, W_o_b, (float*)d_out, Ncnt);
}

// Round 6
// 1421.189 us; speedup vs baseline: 3.5948x; 1.1179x over previous
//
#include <hip/hip_runtime.h>
#include <hip/hip_bf16.h>

#define Ecnt 120000
#define Ncnt 15000
#define Tcnt 500000

typedef __attribute__((ext_vector_type(8))) short short8;
typedef __attribute__((ext_vector_type(4))) float floatx4;

__device__ __forceinline__ floatx4 mfma16(short8 a, short8 b, floatx4 c) {
    return __builtin_amdgcn_mfma_f32_16x16x32_bf16(a, b, c, 0, 0, 0);
}

__device__ __forceinline__ short f2bf(float f) {
    __hip_bfloat16 b = __float2bfloat16(f);
    short s;
    __builtin_memcpy(&s, &b, 2);
    return s;
}

__device__ __forceinline__ float bf2f(short s) {
    unsigned u = ((unsigned)(unsigned short)s) << 16;
    float f;
    __builtin_memcpy(&f, &u, 4);
    return f;
}

__device__ __forceinline__ unsigned pack2(float x, float y) {
    return (unsigned)(unsigned short)f2bf(x) | ((unsigned)(unsigned short)f2bf(y) << 16);
}

// fp32-GEMM LDS swizzle (final concatgemm only)
__device__ __forceinline__ int swz(int k, int r) {
    return k * 68 + (r ^ (((k >> 3) & 7) << 2));
}

// bf16 MFMA tile swizzle: byte-col XOR (row&15)<<4, applied on BOTH sides.
// XOR touches byte bits 4-7 => bijective within any 256-byte-aligned window;
// row stride (shorts) must satisfy: max(bc)^240 < 2*stride.  128-short rows
// (bc<256) and 256-short rows (bc<=304 here) are safe; 160-short rows are NOT
// (round-5 bug: bc=304 ^ 240 = 448 bytes > 320-byte row => corruption).
__device__ __forceinline__ int sidx(int row, int bc) {
    return row * 128 + (((bc) ^ ((row & 15) << 4)) >> 1);
}
__device__ __forceinline__ int sidxg(int row, int bc, int ldshorts) {
    return row * ldshorts + (((bc) ^ ((row & 15) << 4)) >> 1);
}

// stage 64x128 f32 tile -> bf16 swizzled LDS
__device__ __forceinline__ void stage64x128(const float* __restrict__ src, size_t row0,
                                            short* __restrict__ lds, int tid) {
    #pragma unroll
    for (int it = 0; it < 8; ++it) {
        int chunk = tid + it * 256;       // 0..2047
        int r = chunk >> 5, c4 = chunk & 31;
        float4 v = *(const float4*)&src[(row0 + r) * 128 + c4 * 4];
        *(uint2*)&lds[sidx(r, c4 * 8)] = make_uint2(pack2(v.x, v.y), pack2(v.z, v.w));
    }
}

// stage 64x128 bf16 tile -> swizzled LDS (pure move)
__device__ __forceinline__ void stage_bf(const short* __restrict__ src, size_t row0,
                                         short* __restrict__ lds, int tid) {
    #pragma unroll
    for (int it = 0; it < 4; ++it) {
        int chunk = tid + it * 256;       // 0..1023 : 64 rows x 16 groups
        int r = chunk >> 4, cg = chunk & 15;
        uint4 v = *(const uint4*)&src[(row0 + r) * 128 + cg * 8];
        *(uint4*)&lds[sidx(r, cg * 16)] = v;
    }
}

// 16x16 col-tile matmul over K=128 with preloaded A frags
__device__ __forceinline__ floatx4 colmm(const short8 a[4], const short* __restrict__ wp) {
    floatx4 acc = {0.f, 0.f, 0.f, 0.f};
    #pragma unroll
    for (int kb = 0; kb < 4; ++kb)
        acc = mfma16(a[kb], *(const short8*)(wp + kb * 32), acc);
    return acc;
}

// ---------------- small kernels ----------------

__launch_bounds__(256)
__global__ void sentinel_k(float* o, float v) { o[0] = v; }

__launch_bounds__(256)
__global__ void atype_k(const float* __restrict__ af, int* __restrict__ atype) {
    int n = blockIdx.x * 256 + threadIdx.x;
    if (n >= Ncnt) return;
    const float* r = af + (size_t)n * 133;
    int best = 0; float bv = r[0];
    for (int k = 1; k < 100; ++k) { float v = r[k]; if (v > bv) { bv = v; best = k; } }
    atype[n] = best;
}

__launch_bounds__(128)
__global__ void pemb_k(const float* __restrict__ emb, const float* __restrict__ W,
                       float* __restrict__ P1, float* __restrict__ P2) {
    int r = blockIdx.x, c = threadIdx.x;
    __shared__ float er[128];
    er[c] = emb[r * 128 + c];
    __syncthreads();
    float a1 = 0.f, a2 = 0.f;
    for (int k = 0; k < 128; ++k) {
        float e = er[k];
        a1 = fmaf(e, W[k * 128 + c], a1);
        a2 = fmaf(e, W[(128 + k) * 128 + c], a2);
    }
    P1[r * 128 + c] = a1;
    P2[r * 128 + c] = a2;
}

__launch_bounds__(256)
__global__ void rbf0_k(const float* __restrict__ dist, const float* __restrict__ freq,
                       float* __restrict__ rbf0) {
    int e = blockIdx.x * 256 + threadIdx.x;
    if (e >= Ecnt) return;
    float x = dist[e] * 0.125f;
    float x2 = x * x;
    float x5 = x2 * x2 * x;
    float env = 1.f / x - 28.f * x5 + 48.f * x5 * x - 21.f * x5 * x2;
    if (!(x < 1.f)) env = 0.f;
    #pragma unroll
    for (int r = 0; r < 16; ++r)
        rbf0[(size_t)e * 16 + r] = env * sinf(freq[r] * x);
}

__launch_bounds__(256)
__global__ void rbfh_k(const float* __restrict__ rbf0, const float* __restrict__ W,
                       const float* __restrict__ bias, float* __restrict__ Y) {
    int gid = blockIdx.x * 256 + threadIdx.x;
    int e = gid >> 7, c = gid & 127;
    float acc = bias[c];
    #pragma unroll
    for (int k = 0; k < 16; ++k)
        acc = fmaf(rbf0[(size_t)e * 16 + k], W[k * 128 + c], acc);
    Y[(size_t)e * 128 + c] = fmaxf(acc, 0.f);
}

__launch_bounds__(256)
__global__ void scatatom_k(const float* __restrict__ msg, const int* __restrict__ eid,
                           const int* __restrict__ aid, float* __restrict__ am) {
    int gid = blockIdx.x * 256 + threadIdx.x;
    int e = gid >> 7, c = gid & 127;
    float v = msg[(size_t)eid[e] * 128 + c];
    atomicAdd(&am[(size_t)aid[e] * 128 + c], v);
}

// ---------------- sorting ----------------

__launch_bounds__(256)
__global__ void hist_k(const int* __restrict__ idx, int* __restrict__ cnt) {
    int t = blockIdx.x * 256 + threadIdx.x;
    if (t < Tcnt) atomicAdd(&cnt[idx[t]], 1);
}

__launch_bounds__(256)
__global__ void scan1_k(const int* __restrict__ cnt, int* __restrict__ basep,
                        int* __restrict__ btot) {
    __shared__ int s[256];
    int t = threadIdx.x, i = blockIdx.x * 256 + t;
    int v = (i < Ecnt) ? cnt[i] : 0;
    s[t] = v;
    #pragma unroll
    for (int off = 1; off < 256; off <<= 1) {
        __syncthreads();
        int nv = (t >= off) ? s[t - off] + s[t] : s[t];
        __syncthreads();
        s[t] = nv;
    }
    if (i < Ecnt) basep[i] = s[t] - v;
    if (t == 255) btot[blockIdx.x] = s[255];
}

__launch_bounds__(512)
__global__ void scan2_k(const int* __restrict__ btot, int* __restrict__ boff, int nb) {
    __shared__ int s[512];
    int t = threadIdx.x;
    int v = (t < nb) ? btot[t] : 0;
    s[t] = v;
    #pragma unroll
    for (int off = 1; off < 512; off <<= 1) {
        __syncthreads();
        int nv = (t >= off) ? s[t - off] + s[t] : s[t];
        __syncthreads();
        s[t] = nv;
    }
    if (t < nb) boff[t] = s[t] - v;
}

__launch_bounds__(256)
__global__ void scan3_k(const int* __restrict__ basep, const int* __restrict__ boff,
                        int* __restrict__ cur) {
    int i = blockIdx.x * 256 + threadIdx.x;
    if (i < Ecnt) cur[i] = basep[i] + boff[i >> 8];
}

__launch_bounds__(256)
__global__ void perm_k(const int* __restrict__ idx, const float* __restrict__ angle,
                       int* __restrict__ cur, int* __restrict__ eids,
                       float* __restrict__ angs) {
    int t = blockIdx.x * 256 + threadIdx.x;
    if (t >= Tcnt) return;
    int e = idx[t];
    int p = atomicAdd(&cur[e], 1);
    eids[p] = e;
    angs[p] = angle[t];
}

// ---------------- weight conversion (batched) ----------------

struct WPack {
    const float* src[15];
    short* dst[15];
};
__launch_bounds__(256)
__global__ void transmany_k(WPack p) {
    int m = blockIdx.x >> 6;                          // 64 blocks per matrix
    int i = ((blockIdx.x & 63) << 8) + threadIdx.x;   // 0..16383
    int k = i >> 7, c = i & 127;
    p.dst[m][c * 128 + k] = f2bf(p.src[m][k * 128 + c]);
}

__launch_bounds__(256)
__global__ void transcvt_k(const float* __restrict__ W, short* __restrict__ out, int K) {
    int i = blockIdx.x * 256 + threadIdx.x;
    if (i >= K * 128) return;
    int k = i >> 7, c = i & 127;
    out[c * K + k] = f2bf(W[k * 128 + c]);
}

// W_i1 [147][128] f32 -> out [128][160] bf16 transposed, zero-padded K
__launch_bounds__(256)
__global__ void transWi1_k(const float* __restrict__ W, short* __restrict__ out) {
    int i = blockIdx.x * 256 + threadIdx.x;
    if (i >= 128 * 160) return;
    int c = i / 160, k = i % 160;
    out[i] = (k < 147) ? f2bf(W[k * 128 + c]) : (short)0;
}

// ---------------- fused triplet path (bf16 MFMA, sorted, BARRIER-FREE) ----------------
// Each wave owns rows [w*16, w*16+16) of the 64-row tile through all 3 GEMMs:
// every LDS read/write stays in the wave's own band -> no __syncthreads needed,
// single 16KB buffer reused (A-frags preloaded to regs before each overwrite).
__launch_bounds__(256)
__global__ void triplet_mfma_k(const float* __restrict__ angs, const int* __restrict__ eids,
                               const float* __restrict__ rbf0,
                               const short* __restrict__ W1t, const short* __restrict__ W2t,
                               const short* __restrict__ W3t, const float* __restrict__ upB,
                               const short* __restrict__ xdown, float* __restrict__ agg) {
    __shared__ short lds[64 * 128];   // 16 KB
    const int tid = threadIdx.x;
    const int lane = tid & 63;
    const int w = tid >> 6;
    const int row0 = blockIdx.x * 64;
    const int kgrp = lane >> 4;
    const int ccol = lane & 15;
    const int arow = w * 16 + ccol;
    const int cr0  = w * 16 + kgrp * 4;

    // wave-local stage: lane stages quarter kgrp (cols kgrp*24..+24) of row arow
    {
        int srow = row0 + arow;
        float cb[6], rb[16];
        if (srow < Tcnt) {
            float ang = angs[srow];
            int ge = eids[srow];
            float c1 = cosf(ang);
            cb[0] = 1.f; cb[1] = c1;
            #pragma unroll
            for (int a = 2; a < 6; ++a) cb[a] = 2.f * c1 * cb[a - 1] - cb[a - 2];
            #pragma unroll
            for (int i4 = 0; i4 < 4; ++i4) {
                float4 r4 = *(const float4*)&rbf0[(size_t)ge * 16 + i4 * 4];
                rb[i4*4+0] = r4.x; rb[i4*4+1] = r4.y; rb[i4*4+2] = r4.z; rb[i4*4+3] = r4.w;
            }
        } else {
            #pragma unroll
            for (int a = 0; a < 6; ++a) cb[a] = 0.f;
            #pragma unroll
            for (int q = 0; q < 16; ++q) rb[q] = 0.f;
        }
        #pragma unroll
        for (int m = 0; m < 12; ++m) {
            int v0 = kgrp * 24 + 2 * m;
            *(unsigned*)&lds[sidx(arow, 2 * v0)] =
                pack2(cb[v0 >> 4] * rb[v0 & 15], cb[(v0 + 1) >> 4] * rb[(v0 + 1) & 15]);
        }
    }

    int eidc[4];
    #pragma unroll
    for (int j = 0; j < 4; ++j) {
        int sr = row0 + cr0 + j;
        eidc[j] = (sr < Tcnt) ? eids[sr] : -1;
    }

    // early xdown gather (bf16), consumed in GEMM2 epilogue
    float xd[8][4];
    #pragma unroll
    for (int c = 0; c < 8; ++c)
        #pragma unroll
        for (int j = 0; j < 4; ++j)
            xd[c][j] = (eidc[j] >= 0) ? bf2f(xdown[(size_t)eidc[j] * 128 + c * 16 + ccol]) : 0.f;

    // ---- GEMM1: s1 = relu(sbf @ W1), K=96 ----
    {
        short8 a0 = *(const short8*)&lds[sidx(arow, 0   + kgrp * 16)];
        short8 a1 = *(const short8*)&lds[sidx(arow, 64  + kgrp * 16)];
        short8 a2 = *(const short8*)&lds[sidx(arow, 128 + kgrp * 16)];
        #pragma unroll
        for (int c = 0; c < 8; ++c) {
            const short* wp = W1t + (size_t)(c * 16 + ccol) * 96 + kgrp * 8;
            floatx4 acc = {0.f, 0.f, 0.f, 0.f};
            acc = mfma16(a0, *(const short8*)(wp),      acc);
            acc = mfma16(a1, *(const short8*)(wp + 32), acc);
            acc = mfma16(a2, *(const short8*)(wp + 64), acc);
            #pragma unroll
            for (int j = 0; j < 4; ++j)
                lds[sidx(cr0 + j, 2 * (c * 16 + ccol))] = f2bf(fmaxf(acc[j], 0.f));
        }
    }

    // ---- GEMM2: x = relu(s1 @ W2) * xd, K=128 ----
    {
        short8 a[4];
        #pragma unroll
        for (int kb = 0; kb < 4; ++kb)
            a[kb] = *(const short8*)&lds[sidx(arow, kb * 64 + kgrp * 16)];
        #pragma unroll
        for (int c = 0; c < 8; ++c) {
            floatx4 acc = colmm(a, W2t + (size_t)(c * 16 + ccol) * 128 + kgrp * 8);
            #pragma unroll
            for (int j = 0; j < 4; ++j)
                lds[sidx(cr0 + j, 2 * (c * 16 + ccol))] = f2bf(fmaxf(acc[j], 0.f) * xd[c][j]);
        }
    }

    // ---- GEMM3: y = relu(x @ W3 + b), merged atomic scatter ----
    {
        short8 a[4];
        #pragma unroll
        for (int kb = 0; kb < 4; ++kb)
            a[kb] = *(const short8*)&lds[sidx(arow, kb * 64 + kgrp * 16)];
        #pragma unroll
        for (int c = 0; c < 8; ++c) {
            int col = c * 16 + ccol;
            floatx4 acc = colmm(a, W3t + (size_t)col * 128 + kgrp * 8);
            float bv = upB[col];
            float v0 = fmaxf(acc[0] + bv, 0.f);
            float v1 = fmaxf(acc[1] + bv, 0.f);
            float v2 = fmaxf(acc[2] + bv, 0.f);
            float v3 = fmaxf(acc[3] + bv, 0.f);
            if (eidc[0] == eidc[1]) v1 += v0;
            else if (eidc[0] >= 0) atomicAdd(&agg[(size_t)eidc[0] * 128 + col], v0);
            if (eidc[1] == eidc[2]) v2 += v1;
            else if (eidc[1] >= 0) atomicAdd(&agg[(size_t)eidc[1] * 128 + col], v1);
            if (eidc[2] == eidc[3]) v3 += v2;
            else if (eidc[2] >= 0) atomicAdd(&agg[(size_t)eidc[2] * 128 + col], v2);
            if (eidc[3] >= 0) atomicAdd(&agg[(size_t)eidc[3] * 128 + col], v3);
        }
    }
}

// ---------------- initial message: msg = relu([af[j]||ef] @ W_i1 + b), K=160 (pad 147) ----------------
// LDS row stride = 256 shorts (512 B) so the XOR swizzle (bits 4-7, bc<=304)
// stays in-row and bijective (round-5 fix).
__launch_bounds__(256)
__global__ void imsg_k(const float* __restrict__ af, const float* __restrict__ ef,
                       const int* __restrict__ idx_j,
                       const short* __restrict__ Wt, const float* __restrict__ bias,
                       float* __restrict__ msg) {
    __shared__ short lds[64 * 256];    // 32 KB
    const int tid = threadIdx.x;
    const int lane = tid & 63, w = tid >> 6;
    const int row0 = blockIdx.x * 64;

    #pragma unroll
    for (int it = 0; it < 5; ++it) {
        int chunk = tid + it * 256;            // 0..1279 : 64 rows x 20 groups
        int r = chunk / 20, cg = chunk % 20;
        int row = row0 + r;
        int g = idx_j[row];
        unsigned u[4];
        #pragma unroll
        for (int h = 0; h < 4; ++h) {
            int k0 = cg * 8 + 2 * h;
            int k1 = k0 + 1;
            float f0 = (k0 < 133) ? af[(size_t)g * 133 + k0]
                     : (k0 < 147) ? ef[(size_t)row * 14 + (k0 - 133)] : 0.f;
            float f1 = (k1 < 133) ? af[(size_t)g * 133 + k1]
                     : (k1 < 147) ? ef[(size_t)row * 14 + (k1 - 133)] : 0.f;
            u[h] = pack2(f0, f1);
        }
        *(uint4*)&lds[sidxg(r, cg * 16, 256)] = make_uint4(u[0], u[1], u[2], u[3]);
    }
    __syncthreads();

    const int kgrp = lane >> 4, ccol = lane & 15;
    const int arow = w * 16 + ccol;
    const int cr0  = w * 16 + kgrp * 4;
    short8 a[5];
    #pragma unroll
    for (int kb = 0; kb < 5; ++kb)
        a[kb] = *(const short8*)&lds[sidxg(arow, kb * 64 + kgrp * 16, 256)];
    #pragma unroll
    for (int c = 0; c < 8; ++c) {
        int colg = c * 16 + ccol;
        const short* wp = Wt + (size_t)colg * 160 + kgrp * 8;
        floatx4 acc = {0.f, 0.f, 0.f, 0.f};
        #pragma unroll
        for (int kb = 0; kb < 5; ++kb)
            acc = mfma16(a[kb], *(const short8*)(wp + kb * 32), acc);
        float bv = bias[colg];
        #pragma unroll
        for (int j = 0; j < 4; ++j)
            msg[(size_t)(row0 + cr0 + j) * 128 + colg] = fmaxf(acc[j] + bv, 0.f);
    }
}

// ---------------- layerA ----------------
__launch_bounds__(256)
__global__ void layerA_k(const float* __restrict__ msg, const short* __restrict__ rbfe,
                         const short* __restrict__ kjWt, const float* __restrict__ kjB,
                         const short* __restrict__ rbf2Wt, const float* __restrict__ rbf2B,
                         const short* __restrict__ downWt, const float* __restrict__ downB,
                         short* __restrict__ xdown) {
    __shared__ short ldsM[64 * 128];
    __shared__ short ldsR[64 * 128];
    const int tid = threadIdx.x;
    const int lane = tid & 63, w = tid >> 6;
    const size_t row0 = (size_t)blockIdx.x * 64;
    stage64x128(msg, row0, ldsM, tid);
    stage_bf(rbfe, row0, ldsR, tid);
    __syncthreads();
    const int kgrp = lane >> 4, ccol = lane & 15;
    const int arow = w * 16 + ccol;
    const int cr0  = w * 16 + kgrp * 4;
    short8 aM[4], aR[4];
    #pragma unroll
    for (int kb = 0; kb < 4; ++kb) {
        aM[kb] = *(const short8*)&ldsM[sidx(arow, kb * 64 + kgrp * 16)];
        aR[kb] = *(const short8*)&ldsR[sidx(arow, kb * 64 + kgrp * 16)];
    }
    #pragma unroll
    for (int c = 0; c < 8; ++c) {
        int colg = c * 16 + ccol;
        floatx4 ra = colmm(aR, rbf2Wt + (size_t)colg * 128 + kgrp * 8);
        floatx4 ka = colmm(aM, kjWt   + (size_t)colg * 128 + kgrp * 8);
        float rb = rbf2B[colg], kbb = kjB[colg];
        #pragma unroll
        for (int j = 0; j < 4; ++j) {
            float x = fmaxf(ka[j] + kbb, 0.f) * fmaxf(ra[j] + rb, 0.f);
            ldsM[sidx(cr0 + j, 2 * colg)] = f2bf(x);
        }
    }
    __syncthreads();
    short8 aX[4];
    #pragma unroll
    for (int kb = 0; kb < 4; ++kb)
        aX[kb] = *(const short8*)&ldsM[sidx(arow, kb * 64 + kgrp * 16)];
    #pragma unroll
    for (int c = 0; c < 8; ++c) {
        int colg = c * 16 + ccol;
        floatx4 acc = colmm(aX, downWt + (size_t)colg * 128 + kgrp * 8);
        float db = downB[colg];
        #pragma unroll
        for (int j = 0; j < 4; ++j)
            xdown[(row0 + cr0 + j) * 128 + colg] = f2bf(fmaxf(acc[j] + db, 0.f));
    }
}

// ---------------- layerB: msg += agg + relu(relu(agg@r1+b)@r2+b) ----------------
__launch_bounds__(256)
__global__ void layerB_k(const float* __restrict__ agg,
                         const short* __restrict__ r1Wt, const float* __restrict__ r1B,
                         const short* __restrict__ r2Wt, const float* __restrict__ r2B,
                         float* __restrict__ msg) {
    __shared__ short lds[64 * 128];
    const int tid = threadIdx.x;
    const int lane = tid & 63, w = tid >> 6;
    const size_t row0 = (size_t)blockIdx.x * 64;
    stage64x128(agg, row0, lds, tid);
    __syncthreads();
    const int kgrp = lane >> 4, ccol = lane & 15;
    const int arow = w * 16 + ccol;
    const int cr0  = w * 16 + kgrp * 4;
    short8 a1[4];
    #pragma unroll
    for (int kb = 0; kb < 4; ++kb)
        a1[kb] = *(const short8*)&lds[sidx(arow, kb * 64 + kgrp * 16)];
    #pragma unroll
    for (int c = 0; c < 8; ++c) {
        int colg = c * 16 + ccol;
        floatx4 acc = colmm(a1, r1Wt + (size_t)colg * 128 + kgrp * 8);
        float b1 = r1B[colg];
        #pragma unroll
        for (int j = 0; j < 4; ++j)
            lds[sidx(cr0 + j, 2 * colg)] = f2bf(fmaxf(acc[j] + b1, 0.f));
    }
    __syncthreads();
    short8 a2[4];
    #pragma unroll
    for (int kb = 0; kb < 4; ++kb)
        a2[kb] = *(const short8*)&lds[sidx(arow, kb * 64 + kgrp * 16)];
    #pragma unroll
    for (int c = 0; c < 8; ++c) {
        int colg = c * 16 + ccol;
        floatx4 acc = colmm(a2, r2Wt + (size_t)colg * 128 + kgrp * 8);
        float b2 = r2B[colg];
        #pragma unroll
        for (int j = 0; j < 4; ++j) {
            size_t o = (row0 + cr0 + j) * 128 + colg;
            msg[o] = msg[o] + agg[o] + fmaxf(acc[j] + b2, 0.f);
        }
    }
}

// ---------------- rbfe (bf16 out): relu(rbfh@W3 + b + P1[t(i)] + P2[t(j)]) ----------------
__launch_bounds__(256)
__global__ void rbfe_k(const float* __restrict__ rbfh, const short* __restrict__ W3t,
                       const float* __restrict__ bias,
                       const int* __restrict__ idx_i, const int* __restrict__ idx_j,
                       const int* __restrict__ atype,
                       const float* __restrict__ P1, const float* __restrict__ P2,
                       short* __restrict__ out) {
    __shared__ short lds[64 * 128];
    const int tid = threadIdx.x;
    const int lane = tid & 63, w = tid >> 6;
    const size_t row0 = (size_t)blockIdx.x * 64;
    stage64x128(rbfh, row0, lds, tid);
    const int kgrp = lane >> 4, ccol = lane & 15;
    const int arow = w * 16 + ccol;
    const int cr0  = w * 16 + kgrp * 4;
    const float* p1p[4]; const float* p2p[4];
    #pragma unroll
    for (int j = 0; j < 4; ++j) {
        size_t row = row0 + cr0 + j;
        p1p[j] = P1 + (size_t)atype[idx_i[row]] * 128;
        p2p[j] = P2 + (size_t)atype[idx_j[row]] * 128;
    }
    __syncthreads();
    short8 a[4];
    #pragma unroll
    for (int kb = 0; kb < 4; ++kb)
        a[kb] = *(const short8*)&lds[sidx(arow, kb * 64 + kgrp * 16)];
    #pragma unroll
    for (int c = 0; c < 8; ++c) {
        int colg = c * 16 + ccol;
        floatx4 acc = colmm(a, W3t + (size_t)colg * 128 + kgrp * 8);
        float bv = bias[colg];
        #pragma unroll
        for (int j = 0; j < 4; ++j)
            out[(row0 + cr0 + j) * 128 + colg] =
                f2bf(fmaxf(acc[j] + bv + p1p[j][colg] + p2p[j][colg], 0.f));
    }
}

// ---------------- concat GEMM (fp32, final projection only) ----------------
template<bool GATHER>
__launch_bounds__(256)
__global__ void concatgemm_k(const float* __restrict__ IN1, int K1,
                             const float* __restrict__ IN2, int K2,
                             const int* __restrict__ gidx,
                             const float* __restrict__ W, const float* __restrict__ bias,
                             float* __restrict__ Y, int M) {
    __shared__ float xs[96 * 68];
    const int tid = threadIdx.x;
    const int row0 = blockIdx.x * 64;
    const int col8 = (tid & 15) * 8;
    const int r0 = (tid >> 4) * 4;
    const int K = K1 + K2;

    float acc[4][8];
    #pragma unroll
    for (int r = 0; r < 4; ++r)
        #pragma unroll
        for (int c = 0; c < 8; ++c) acc[r][c] = 0.f;

    for (int kb = 0; kb < K; kb += 96) {
        int kc = (K - kb < 96) ? (K - kb) : 96;
        __syncthreads();
        for (int idx = tid; idx < 64 * 96; idx += 256) {
            int r = idx / 96, kl = idx % 96;
            if (kl < kc) {
                int row = row0 + r;
                float v = 0.f;
                if (row < M) {
                    int kg = kb + kl;
                    if (kg < K1) {
                        int g = GATHER ? gidx[row] : row;
                        v = IN1[(size_t)g * K1 + kg];
                    } else {
                        v = IN2[(size_t)row * K2 + (kg - K1)];
                    }
                }
                xs[kl * 68 + r] = v;
            }
        }
        __syncthreads();
        for (int k = 0; k < kc; ++k) {
            float4 xv = *(const float4*)&xs[k * 68 + r0];
            const float* wr = &W[(size_t)(kb + k) * 128 + col8];
            float4 w0 = *(const float4*)wr;
            float4 w1 = *(const float4*)(wr + 4);
            float xr[4] = {xv.x, xv.y, xv.z, xv.w};
            float wc[8] = {w0.x, w0.y, w0.z, w0.w, w1.x, w1.y, w1.z, w1.w};
            #pragma unroll
            for (int r = 0; r < 4; ++r)
                #pragma unroll
                for (int c = 0; c < 8; ++c)
                    acc[r][c] = fmaf(xr[r], wc[c], acc[r][c]);
        }
    }

    float4 b0 = *(const float4*)&bias[col8];
    float4 b1 = *(const float4*)&bias[col8 + 4];
    float bb[8] = {b0.x, b0.y, b0.z, b0.w, b1.x, b1.y, b1.z, b1.w};
    #pragma unroll
    for (int r = 0; r < 4; ++r) {
        int row = row0 + r0 + r;
        if (row >= M) continue;
        float v[8];
        #pragma unroll
        for (int c = 0; c < 8; ++c) v[c] = fmaxf(acc[r][c] + bb[c], 0.f);
        *(float4*)&Y[(size_t)row * 128 + col8]     = make_float4(v[0], v[1], v[2], v[3]);
        *(float4*)&Y[(size_t)row * 128 + col8 + 4] = make_float4(v[4], v[5], v[6], v[7]);
    }
}

// ---------------- host ----------------

extern "C" void kernel_launch(void* const* d_in, const int* in_sizes, int n_in,
                              void* d_out, int out_size, void* d_ws, size_t ws_size,
                              hipStream_t stream) {
    const float* atom_feature = (const float*)d_in[0];
    const float* edge_feature = (const float*)d_in[1];
    const float* dist         = (const float*)d_in[2];
    const float* angle        = (const float*)d_in[3];
    const float* W_i1_w       = (const float*)d_in[4];
    const float* W_i1_b       = (const float*)d_in[5];
    const float* emb_table    = (const float*)d_in[6];
    const float* lin_rbf_w    = (const float*)d_in[7];
    const float* lin_rbf_b    = (const float*)d_in[8];
    const float* lin_emb_w    = (const float*)d_in[9];
    const float* lin_emb_b    = (const float*)d_in[10];
    const float* bessel_freq  = (const float*)d_in[11];
    const float* L_rbf2_w     = (const float*)d_in[12];
    const float* L_rbf2_b     = (const float*)d_in[13];
    const float* L_kj_w       = (const float*)d_in[14];
    const float* L_kj_b       = (const float*)d_in[15];
    const float* L_sbf1_w     = (const float*)d_in[16];
    const float* L_sbf2_w     = (const float*)d_in[17];
    const float* L_down_w     = (const float*)d_in[18];
    const float* L_down_b     = (const float*)d_in[19];
    const float* L_up_w       = (const float*)d_in[20];
    const float* L_up_b       = (const float*)d_in[21];
    const float* L_res1_w     = (const float*)d_in[22];
    const float* L_res1_b     = (const float*)d_in[23];
    const float* L_res2_w     = (const float*)d_in[24];
    const float* L_res2_b     = (const float*)d_in[25];
    const float* W_o_w        = (const float*)d_in[26];
    const float* W_o_b        = (const float*)d_in[27];
    const int* idx_i          = (const int*)d_in[28];
    const int* idx_j          = (const int*)d_in[29];
    const int* idx_kj         = (const int*)d_in[30];
    const int* ib_eid         = (const int*)d_in[32];
    const int* ib_atom        = (const int*)d_in[33];

    float* ws = (float*)d_ws;
    size_t off = 0;
    auto take = [&](size_t n) { float* p = ws + off; off += n; return p; };
    float* msg   = take((size_t)Ecnt * 128);
    short* rbfe  = (short*)take((size_t)Ecnt * 64);   // bf16 [E][128]
    float* agg   = take((size_t)Ecnt * 128);          // also rbf_h temp
    short* sxd   = (short*)take((size_t)Ecnt * 64);   // bf16 xdown
    float* rbf0b = take((size_t)Ecnt * 16);
    float* atomm = take((size_t)Ncnt * 128);
    float* P1    = take(100 * 128);
    float* P2    = take(100 * 128);
    int*   atyp  = (int*)take(Ncnt);
    int*   cnts  = (int*)take(Ecnt);
    int*   basep = (int*)take(Ecnt);
    int*   cur   = (int*)take(Ecnt);
    int*   btot  = (int*)take(512);
    int*   boff  = (int*)take(512);
    int*   eids  = (int*)take(Tcnt);
    float* angs  = take(Tcnt);
    short* wts   = (short*)take(160000);   // 290816 shorts needed; 320000 given

    if (off * sizeof(float) > ws_size) {
        sentinel_k<<<1, 256, 0, stream>>>((float*)d_out, (float)ws_size);
        return;
    }

    const int GE  = Ecnt / 64;            // 1875 exact
    const int GN  = (Ncnt + 63) / 64;     // 235
    const int GT  = (Tcnt + 63) / 64;     // 7813
    const int NBE = (Ecnt + 255) / 256;
    const int NBT = (Tcnt + 255) / 256;

    // --- prep ---
    atype_k<<<(Ncnt + 255) / 256, 256, 0, stream>>>(atom_feature, atyp);
    pemb_k<<<100, 128, 0, stream>>>(emb_table, lin_emb_w, P1, P2);
    rbf0_k<<<NBE, 256, 0, stream>>>(dist, bessel_freq, rbf0b);

    hipMemsetAsync(cnts, 0, (size_t)Ecnt * sizeof(int), stream);
    hist_k<<<NBT, 256, 0, stream>>>(idx_kj, cnts);
    scan1_k<<<NBE, 256, 0, stream>>>(cnts, basep, btot);
    scan2_k<<<1, 512, 0, stream>>>(btot, boff, NBE);
    scan3_k<<<NBE, 256, 0, stream>>>(basep, boff, cur);
    perm_k<<<NBT, 256, 0, stream>>>(idx_kj, angle, cur, eids, angs);

    // --- bf16 transposed weights ---
    short* p = wts;
    short* wt1[2]; short* wt2[2]; short* wt3[2];
    short* wkj[2]; short* wr2f[2]; short* wdn[2]; short* wr1[2]; short* wr2[2];
    for (int l = 0; l < 2; ++l) {
        wt1[l] = p; p += 96 * 128;
        wt2[l] = p; p += 128 * 128;
        wt3[l] = p; p += 128 * 128;
        wkj[l] = p; p += 128 * 128;
        wr2f[l] = p; p += 128 * 128;
        wdn[l] = p; p += 128 * 128;
        wr1[l] = p; p += 128 * 128;
        wr2[l] = p; p += 128 * 128;
    }
    short* wemb3 = p; p += 128 * 128;
    short* wi1t  = p; p += 128 * 160;

    WPack wp;
    int m = 0;
    for (int l = 0; l < 2; ++l) {
        wp.src[m] = L_sbf2_w + (size_t)l * 128 * 128; wp.dst[m++] = wt2[l];
        wp.src[m] = L_up_w   + (size_t)l * 128 * 128; wp.dst[m++] = wt3[l];
        wp.src[m] = L_kj_w   + (size_t)l * 128 * 128; wp.dst[m++] = wkj[l];
        wp.src[m] = L_rbf2_w + (size_t)l * 128 * 128; wp.dst[m++] = wr2f[l];
        wp.src[m] = L_down_w + (size_t)l * 128 * 128; wp.dst[m++] = wdn[l];
        wp.src[m] = L_res1_w + (size_t)l * 128 * 128; wp.dst[m++] = wr1[l];
        wp.src[m] = L_res2_w + (size_t)l * 128 * 128; wp.dst[m++] = wr2[l];
    }
    wp.src[m] = lin_emb_w + 256 * 128; wp.dst[m++] = wemb3;   // m == 15
    transmany_k<<<15 * 64, 256, 0, stream>>>(wp);
    const int G96 = (96 * 128 + 255) / 256;
    transcvt_k<<<G96, 256, 0, stream>>>(L_sbf1_w, wt1[0], 96);
    transcvt_k<<<G96, 256, 0, stream>>>(L_sbf1_w + (size_t)96 * 128, wt1[1], 96);
    transWi1_k<<<(128 * 160 + 255) / 256, 256, 0, stream>>>(W_i1_w, wi1t);

    // --- initial message + rbf_e ---
    imsg_k<<<GE, 256, 0, stream>>>(atom_feature, edge_feature, idx_j, wi1t, W_i1_b, msg);
    rbfh_k<<<(Ecnt * 128) / 256, 256, 0, stream>>>(rbf0b, lin_rbf_w, lin_rbf_b, agg);
    rbfe_k<<<GE, 256, 0, stream>>>(agg, wemb3, lin_emb_b, idx_i, idx_j, atyp, P1, P2, rbfe);

    for (int l = 0; l < 2; ++l) {
        layerA_k<<<GE, 256, 0, stream>>>(msg, rbfe,
                                         wkj[l], L_kj_b + (size_t)l * 128,
                                         wr2f[l], L_rbf2_b + (size_t)l * 128,
                                         wdn[l], L_down_b + (size_t)l * 128, sxd);
        hipMemsetAsync(agg, 0, (size_t)Ecnt * 128 * sizeof(float), stream);
        triplet_mfma_k<<<GT, 256, 0, stream>>>(angs, eids, rbf0b,
                                               wt1[l], wt2[l], wt3[l],
                                               L_up_b + (size_t)l * 128, sxd, agg);
        layerB_k<<<GE, 256, 0, stream>>>(agg,
                                         wr1[l], L_res1_b + (size_t)l * 128,
                                         wr2[l], L_res2_b + (size_t)l * 128, msg);
    }

    // atom_message scatter + final projection
    hipMemsetAsync(atomm, 0, (size_t)Ncnt * 128 * sizeof(float), stream);
    scatatom_k<<<(Ecnt * 128) / 256, 256, 0, stream>>>(msg, ib_eid, ib_atom, atomm);
    concatgemm_k<false><<<GN, 256, 0, stream>>>(atom_feature, 133, atomm, 128,
                                                nullptr, W_o_w, W_o_b, (float*)d_out, Ncnt);
}

// Round 7
// 1400.041 us; speedup vs baseline: 3.6491x; 1.0151x over previous
//
#include <hip/hip_runtime.h>
#include <hip/hip_bf16.h>

#define Ecnt 120000
#define Ncnt 15000
#define Tcnt 500000

typedef __attribute__((ext_vector_type(8))) short short8;
typedef __attribute__((ext_vector_type(4))) float floatx4;

__device__ __forceinline__ floatx4 mfma16(short8 a, short8 b, floatx4 c) {
    return __builtin_amdgcn_mfma_f32_16x16x32_bf16(a, b, c, 0, 0, 0);
}

__device__ __forceinline__ short f2bf(float f) {
    __hip_bfloat16 b = __float2bfloat16(f);
    short s;
    __builtin_memcpy(&s, &b, 2);
    return s;
}

__device__ __forceinline__ float bf2f(short s) {
    unsigned u = ((unsigned)(unsigned short)s) << 16;
    float f;
    __builtin_memcpy(&f, &u, 4);
    return f;
}

__device__ __forceinline__ unsigned pack2(float x, float y) {
    return (unsigned)(unsigned short)f2bf(x) | ((unsigned)(unsigned short)f2bf(y) << 16);
}

// fp32-GEMM LDS swizzle (final concatgemm only)
__device__ __forceinline__ int swz(int k, int r) {
    return k * 68 + (r ^ (((k >> 3) & 7) << 2));
}

// bf16 MFMA tile swizzle: byte-col XOR (row&15)<<4, applied on BOTH sides.
// Bijective within 256-byte-aligned windows; row stride must keep bc^240 in-row
// (128-short rows: bc<256 ok; 256-short rows: bc<=304 ok; 160-short rows NOT).
__device__ __forceinline__ int sidx(int row, int bc) {
    return row * 128 + (((bc) ^ ((row & 15) << 4)) >> 1);
}
__device__ __forceinline__ int sidxg(int row, int bc, int ldshorts) {
    return row * ldshorts + (((bc) ^ ((row & 15) << 4)) >> 1);
}

// stage 64x128 f32 tile -> bf16 swizzled LDS
__device__ __forceinline__ void stage64x128(const float* __restrict__ src, size_t row0,
                                            short* __restrict__ lds, int tid) {
    #pragma unroll
    for (int it = 0; it < 8; ++it) {
        int chunk = tid + it * 256;       // 0..2047
        int r = chunk >> 5, c4 = chunk & 31;
        float4 v = *(const float4*)&src[(row0 + r) * 128 + c4 * 4];
        *(uint2*)&lds[sidx(r, c4 * 8)] = make_uint2(pack2(v.x, v.y), pack2(v.z, v.w));
    }
}

// stage 64x128 bf16 tile -> swizzled LDS (pure move)
__device__ __forceinline__ void stage_bf(const short* __restrict__ src, size_t row0,
                                         short* __restrict__ lds, int tid) {
    #pragma unroll
    for (int it = 0; it < 4; ++it) {
        int chunk = tid + it * 256;       // 0..1023 : 64 rows x 16 groups
        int r = chunk >> 4, cg = chunk & 15;
        uint4 v = *(const uint4*)&src[(row0 + r) * 128 + cg * 8];
        *(uint4*)&lds[sidx(r, cg * 16)] = v;
    }
}

// ---- 8-column-tile GEMM with 2-deep weight prefetch (T3/T4-style, plain HIP) ----
// a[NKB]: this lane's A fragments (K = NKB*32). wcol = Wt + ccol*K + kgrp*8.
// Column tile c lives at wcol + c*16*K. Rotating 2-buffer prefetch keeps 2
// column-tiles of weights in flight while MFMAs consume the previous one.
template<int NKB, int K>
__device__ __forceinline__ void colmm8_pf(const short8 a[NKB], const short* __restrict__ wcol,
                                          floatx4 out[8]) {
    short8 w[2][NKB];
    #pragma unroll
    for (int kb = 0; kb < NKB; ++kb) w[0][kb] = *(const short8*)(wcol + kb * 32);
    #pragma unroll
    for (int kb = 0; kb < NKB; ++kb) w[1][kb] = *(const short8*)(wcol + 16 * K + kb * 32);
    #pragma unroll
    for (int c = 0; c < 8; ++c) {
        floatx4 acc = {0.f, 0.f, 0.f, 0.f};
        #pragma unroll
        for (int kb = 0; kb < NKB; ++kb) acc = mfma16(a[kb], w[c & 1][kb], acc);
        out[c] = acc;
        if (c + 2 < 8) {
            #pragma unroll
            for (int kb = 0; kb < NKB; ++kb)
                w[c & 1][kb] = *(const short8*)(wcol + (size_t)(c + 2) * 16 * K + kb * 32);
        }
    }
}

// ---------------- small kernels ----------------

__launch_bounds__(256)
__global__ void sentinel_k(float* o, float v) { o[0] = v; }

__launch_bounds__(256)
__global__ void atype_k(const float* __restrict__ af, int* __restrict__ atype) {
    int n = blockIdx.x * 256 + threadIdx.x;
    if (n >= Ncnt) return;
    const float* r = af + (size_t)n * 133;
    int best = 0; float bv = r[0];
    for (int k = 1; k < 100; ++k) { float v = r[k]; if (v > bv) { bv = v; best = k; } }
    atype[n] = best;
}

__launch_bounds__(128)
__global__ void pemb_k(const float* __restrict__ emb, const float* __restrict__ W,
                       float* __restrict__ P1, float* __restrict__ P2) {
    int r = blockIdx.x, c = threadIdx.x;
    __shared__ float er[128];
    er[c] = emb[r * 128 + c];
    __syncthreads();
    float a1 = 0.f, a2 = 0.f;
    for (int k = 0; k < 128; ++k) {
        float e = er[k];
        a1 = fmaf(e, W[k * 128 + c], a1);
        a2 = fmaf(e, W[(128 + k) * 128 + c], a2);
    }
    P1[r * 128 + c] = a1;
    P2[r * 128 + c] = a2;
}

__launch_bounds__(256)
__global__ void rbf0_k(const float* __restrict__ dist, const float* __restrict__ freq,
                       float* __restrict__ rbf0) {
    int e = blockIdx.x * 256 + threadIdx.x;
    if (e >= Ecnt) return;
    float x = dist[e] * 0.125f;
    float x2 = x * x;
    float x5 = x2 * x2 * x;
    float env = 1.f / x - 28.f * x5 + 48.f * x5 * x - 21.f * x5 * x2;
    if (!(x < 1.f)) env = 0.f;
    #pragma unroll
    for (int r = 0; r < 16; ++r)
        rbf0[(size_t)e * 16 + r] = env * sinf(freq[r] * x);
}

__launch_bounds__(256)
__global__ void rbfh_k(const float* __restrict__ rbf0, const float* __restrict__ W,
                       const float* __restrict__ bias, float* __restrict__ Y) {
    int gid = blockIdx.x * 256 + threadIdx.x;
    int e = gid >> 7, c = gid & 127;
    float acc = bias[c];
    #pragma unroll
    for (int k = 0; k < 16; ++k)
        acc = fmaf(rbf0[(size_t)e * 16 + k], W[k * 128 + c], acc);
    Y[(size_t)e * 128 + c] = fmaxf(acc, 0.f);
}

__launch_bounds__(256)
__global__ void scatatom_k(const float* __restrict__ msg, const int* __restrict__ eid,
                           const int* __restrict__ aid, float* __restrict__ am) {
    int gid = blockIdx.x * 256 + threadIdx.x;
    int e = gid >> 7, c = gid & 127;
    float v = msg[(size_t)eid[e] * 128 + c];
    atomicAdd(&am[(size_t)aid[e] * 128 + c], v);
}

// ---------------- sorting ----------------

__launch_bounds__(256)
__global__ void hist_k(const int* __restrict__ idx, int* __restrict__ cnt) {
    int t = blockIdx.x * 256 + threadIdx.x;
    if (t < Tcnt) atomicAdd(&cnt[idx[t]], 1);
}

__launch_bounds__(256)
__global__ void scan1_k(const int* __restrict__ cnt, int* __restrict__ basep,
                        int* __restrict__ btot) {
    __shared__ int s[256];
    int t = threadIdx.x, i = blockIdx.x * 256 + t;
    int v = (i < Ecnt) ? cnt[i] : 0;
    s[t] = v;
    #pragma unroll
    for (int off = 1; off < 256; off <<= 1) {
        __syncthreads();
        int nv = (t >= off) ? s[t - off] + s[t] : s[t];
        __syncthreads();
        s[t] = nv;
    }
    if (i < Ecnt) basep[i] = s[t] - v;
    if (t == 255) btot[blockIdx.x] = s[255];
}

__launch_bounds__(512)
__global__ void scan2_k(const int* __restrict__ btot, int* __restrict__ boff, int nb) {
    __shared__ int s[512];
    int t = threadIdx.x;
    int v = (t < nb) ? btot[t] : 0;
    s[t] = v;
    #pragma unroll
    for (int off = 1; off < 512; off <<= 1) {
        __syncthreads();
        int nv = (t >= off) ? s[t - off] + s[t] : s[t];
        __syncthreads();
        s[t] = nv;
    }
    if (t < nb) boff[t] = s[t] - v;
}

__launch_bounds__(256)
__global__ void scan3_k(const int* __restrict__ basep, const int* __restrict__ boff,
                        int* __restrict__ cur) {
    int i = blockIdx.x * 256 + threadIdx.x;
    if (i < Ecnt) cur[i] = basep[i] + boff[i >> 8];
}

__launch_bounds__(256)
__global__ void perm_k(const int* __restrict__ idx, const float* __restrict__ angle,
                       int* __restrict__ cur, int* __restrict__ eids,
                       float* __restrict__ angs) {
    int t = blockIdx.x * 256 + threadIdx.x;
    if (t >= Tcnt) return;
    int e = idx[t];
    int p = atomicAdd(&cur[e], 1);
    eids[p] = e;
    angs[p] = angle[t];
}

// ---------------- weight conversion (batched) ----------------

struct WPack {
    const float* src[15];
    short* dst[15];
};
__launch_bounds__(256)
__global__ void transmany_k(WPack p) {
    int m = blockIdx.x >> 6;                          // 64 blocks per matrix
    int i = ((blockIdx.x & 63) << 8) + threadIdx.x;   // 0..16383
    int k = i >> 7, c = i & 127;
    p.dst[m][c * 128 + k] = f2bf(p.src[m][k * 128 + c]);
}

__launch_bounds__(256)
__global__ void transcvt_k(const float* __restrict__ W, short* __restrict__ out, int K) {
    int i = blockIdx.x * 256 + threadIdx.x;
    if (i >= K * 128) return;
    int k = i >> 7, c = i & 127;
    out[c * K + k] = f2bf(W[k * 128 + c]);
}

// W_i1 [147][128] f32 -> out [128][160] bf16 transposed, zero-padded K
__launch_bounds__(256)
__global__ void transWi1_k(const float* __restrict__ W, short* __restrict__ out) {
    int i = blockIdx.x * 256 + threadIdx.x;
    if (i >= 128 * 160) return;
    int c = i / 160, k = i % 160;
    out[i] = (k < 147) ? f2bf(W[k * 128 + c]) : (short)0;
}

// ---------------- fused triplet path (bf16 MFMA, sorted, barrier-free, prefetched) ----------------
// xdown layout is TRANSPOSED-per-row: xdown[e*128 + ccol*8 + c] so each lane's
// 8 c-values for a row are one contiguous 16B load.
__launch_bounds__(256, 3)
__global__ void triplet_mfma_k(const float* __restrict__ angs, const int* __restrict__ eids,
                               const float* __restrict__ rbf0,
                               const short* __restrict__ W1t, const short* __restrict__ W2t,
                               const short* __restrict__ W3t, const float* __restrict__ upB,
                               const short* __restrict__ xdown, float* __restrict__ agg) {
    __shared__ short lds[64 * 128];   // 16 KB
    const int tid = threadIdx.x;
    const int lane = tid & 63;
    const int w = tid >> 6;
    const int row0 = blockIdx.x * 64;
    const int kgrp = lane >> 4;
    const int ccol = lane & 15;
    const int arow = w * 16 + ccol;
    const int cr0  = w * 16 + kgrp * 4;

    // wave-local stage: lane stages quarter kgrp (cols kgrp*24..+24) of row arow
    {
        int srow = row0 + arow;
        float cb[6], rb[16];
        if (srow < Tcnt) {
            float ang = angs[srow];
            int ge = eids[srow];
            float c1 = cosf(ang);
            cb[0] = 1.f; cb[1] = c1;
            #pragma unroll
            for (int a = 2; a < 6; ++a) cb[a] = 2.f * c1 * cb[a - 1] - cb[a - 2];
            #pragma unroll
            for (int i4 = 0; i4 < 4; ++i4) {
                float4 r4 = *(const float4*)&rbf0[(size_t)ge * 16 + i4 * 4];
                rb[i4*4+0] = r4.x; rb[i4*4+1] = r4.y; rb[i4*4+2] = r4.z; rb[i4*4+3] = r4.w;
            }
        } else {
            #pragma unroll
            for (int a = 0; a < 6; ++a) cb[a] = 0.f;
            #pragma unroll
            for (int q = 0; q < 16; ++q) rb[q] = 0.f;
        }
        #pragma unroll
        for (int m = 0; m < 12; ++m) {
            int v0 = kgrp * 24 + 2 * m;
            *(unsigned*)&lds[sidx(arow, 2 * v0)] =
                pack2(cb[v0 >> 4] * rb[v0 & 15], cb[(v0 + 1) >> 4] * rb[(v0 + 1) & 15]);
        }
    }

    int eidc[4];
    #pragma unroll
    for (int j = 0; j < 4; ++j) {
        int sr = row0 + cr0 + j;
        eidc[j] = (sr < Tcnt) ? eids[sr] : -1;
    }

    // early xdown gather: 4 x 16B (transposed layout), consumed after GEMM2
    short8 xds[4];
    #pragma unroll
    for (int j = 0; j < 4; ++j) {
        if (eidc[j] >= 0)
            xds[j] = *(const short8*)&xdown[(size_t)eidc[j] * 128 + ccol * 8];
        else
            xds[j] = short8{0, 0, 0, 0, 0, 0, 0, 0};
    }

    floatx4 o[8];

    // ---- GEMM1: s1 = relu(sbf @ W1), K=96 ----
    {
        short8 a3[3];
        #pragma unroll
        for (int kb = 0; kb < 3; ++kb)
            a3[kb] = *(const short8*)&lds[sidx(arow, kb * 64 + kgrp * 16)];
        colmm8_pf<3, 96>(a3, W1t + ccol * 96 + kgrp * 8, o);
        #pragma unroll
        for (int c = 0; c < 8; ++c)
            #pragma unroll
            for (int j = 0; j < 4; ++j)
                lds[sidx(cr0 + j, 2 * (c * 16 + ccol))] = f2bf(fmaxf(o[c][j], 0.f));
    }

    // ---- GEMM2: x = relu(s1 @ W2) * xd, K=128 ----
    {
        short8 a4[4];
        #pragma unroll
        for (int kb = 0; kb < 4; ++kb)
            a4[kb] = *(const short8*)&lds[sidx(arow, kb * 64 + kgrp * 16)];
        colmm8_pf<4, 128>(a4, W2t + ccol * 128 + kgrp * 8, o);
        #pragma unroll
        for (int c = 0; c < 8; ++c)
            #pragma unroll
            for (int j = 0; j < 4; ++j)
                lds[sidx(cr0 + j, 2 * (c * 16 + ccol))] =
                    f2bf(fmaxf(o[c][j], 0.f) * bf2f(xds[j][c]));
    }

    // ---- GEMM3: y = relu(x @ W3 + b), merged atomic scatter ----
    {
        short8 a4[4];
        #pragma unroll
        for (int kb = 0; kb < 4; ++kb)
            a4[kb] = *(const short8*)&lds[sidx(arow, kb * 64 + kgrp * 16)];
        colmm8_pf<4, 128>(a4, W3t + ccol * 128 + kgrp * 8, o);
        #pragma unroll
        for (int c = 0; c < 8; ++c) {
            int col = c * 16 + ccol;
            float bv = upB[col];
            float v0 = fmaxf(o[c][0] + bv, 0.f);
            float v1 = fmaxf(o[c][1] + bv, 0.f);
            float v2 = fmaxf(o[c][2] + bv, 0.f);
            float v3 = fmaxf(o[c][3] + bv, 0.f);
            if (eidc[0] == eidc[1]) v1 += v0;
            else if (eidc[0] >= 0) atomicAdd(&agg[(size_t)eidc[0] * 128 + col], v0);
            if (eidc[1] == eidc[2]) v2 += v1;
            else if (eidc[1] >= 0) atomicAdd(&agg[(size_t)eidc[1] * 128 + col], v1);
            if (eidc[2] == eidc[3]) v3 += v2;
            else if (eidc[2] >= 0) atomicAdd(&agg[(size_t)eidc[2] * 128 + col], v2);
            if (eidc[3] >= 0) atomicAdd(&agg[(size_t)eidc[3] * 128 + col], v3);
        }
    }
}

// ---------------- initial message: msg = relu([af[j]||ef] @ W_i1 + b), K=160 ----------------
__launch_bounds__(256, 3)
__global__ void imsg_k(const float* __restrict__ af, const float* __restrict__ ef,
                       const int* __restrict__ idx_j,
                       const short* __restrict__ Wt, const float* __restrict__ bias,
                       float* __restrict__ msg) {
    __shared__ short lds[64 * 256];    // 32 KB (512B rows keep swizzle bijective)
    const int tid = threadIdx.x;
    const int lane = tid & 63, w = tid >> 6;
    const int row0 = blockIdx.x * 64;

    #pragma unroll
    for (int it = 0; it < 5; ++it) {
        int chunk = tid + it * 256;            // 0..1279 : 64 rows x 20 groups
        int r = chunk / 20, cg = chunk % 20;
        int row = row0 + r;
        int g = idx_j[row];
        unsigned u[4];
        #pragma unroll
        for (int h = 0; h < 4; ++h) {
            int k0 = cg * 8 + 2 * h;
            int k1 = k0 + 1;
            float f0 = (k0 < 133) ? af[(size_t)g * 133 + k0]
                     : (k0 < 147) ? ef[(size_t)row * 14 + (k0 - 133)] : 0.f;
            float f1 = (k1 < 133) ? af[(size_t)g * 133 + k1]
                     : (k1 < 147) ? ef[(size_t)row * 14 + (k1 - 133)] : 0.f;
            u[h] = pack2(f0, f1);
        }
        *(uint4*)&lds[sidxg(r, cg * 16, 256)] = make_uint4(u[0], u[1], u[2], u[3]);
    }
    __syncthreads();

    const int kgrp = lane >> 4, ccol = lane & 15;
    const int arow = w * 16 + ccol;
    const int cr0  = w * 16 + kgrp * 4;
    short8 a[5];
    #pragma unroll
    for (int kb = 0; kb < 5; ++kb)
        a[kb] = *(const short8*)&lds[sidxg(arow, kb * 64 + kgrp * 16, 256)];
    floatx4 o[8];
    colmm8_pf<5, 160>(a, Wt + ccol * 160 + kgrp * 8, o);
    #pragma unroll
    for (int c = 0; c < 8; ++c) {
        int colg = c * 16 + ccol;
        float bv = bias[colg];
        #pragma unroll
        for (int j = 0; j < 4; ++j)
            msg[(size_t)(row0 + cr0 + j) * 128 + colg] = fmaxf(o[c][j] + bv, 0.f);
    }
}

// ---------------- layerA: xdown = relu((relu(msg@kjW+b) * relu(rbfe@rbf2W+b)) @ downW + b) ----------------
// xdown written in TRANSPOSED-per-row layout (16B packed per row per lane).
__launch_bounds__(256, 3)
__global__ void layerA_k(const float* __restrict__ msg, const short* __restrict__ rbfe,
                         const short* __restrict__ kjWt, const float* __restrict__ kjB,
                         const short* __restrict__ rbf2Wt, const float* __restrict__ rbf2B,
                         const short* __restrict__ downWt, const float* __restrict__ downB,
                         short* __restrict__ xdown) {
    __shared__ short ldsM[64 * 128];
    __shared__ short ldsR[64 * 128];
    const int tid = threadIdx.x;
    const int lane = tid & 63, w = tid >> 6;
    const size_t row0 = (size_t)blockIdx.x * 64;
    stage64x128(msg, row0, ldsM, tid);
    stage_bf(rbfe, row0, ldsR, tid);
    __syncthreads();
    const int kgrp = lane >> 4, ccol = lane & 15;
    const int arow = w * 16 + ccol;
    const int cr0  = w * 16 + kgrp * 4;
    short8 aM[4], aR[4];
    #pragma unroll
    for (int kb = 0; kb < 4; ++kb) {
        aM[kb] = *(const short8*)&ldsM[sidx(arow, kb * 64 + kgrp * 16)];
        aR[kb] = *(const short8*)&ldsR[sidx(arow, kb * 64 + kgrp * 16)];
    }
    floatx4 oR[8], oK[8];
    colmm8_pf<4, 128>(aR, rbf2Wt + ccol * 128 + kgrp * 8, oR);
    colmm8_pf<4, 128>(aM, kjWt   + ccol * 128 + kgrp * 8, oK);
    #pragma unroll
    for (int c = 0; c < 8; ++c) {
        int colg = c * 16 + ccol;
        float rb = rbf2B[colg], kbb = kjB[colg];
        #pragma unroll
        for (int j = 0; j < 4; ++j) {
            float x = fmaxf(oK[c][j] + kbb, 0.f) * fmaxf(oR[c][j] + rb, 0.f);
            ldsM[sidx(cr0 + j, 2 * colg)] = f2bf(x);
        }
    }
    // wave-band-local: no barrier needed
    short8 aX[4];
    #pragma unroll
    for (int kb = 0; kb < 4; ++kb)
        aX[kb] = *(const short8*)&ldsM[sidx(arow, kb * 64 + kgrp * 16)];
    colmm8_pf<4, 128>(aX, downWt + ccol * 128 + kgrp * 8, oK);
    #pragma unroll
    for (int j = 0; j < 4; ++j) {
        short8 v;
        #pragma unroll
        for (int c = 0; c < 8; ++c)
            v[c] = f2bf(fmaxf(oK[c][j] + downB[c * 16 + ccol], 0.f));
        *(short8*)&xdown[(row0 + cr0 + j) * 128 + ccol * 8] = v;
    }
}

// ---------------- layerB: msg += agg + relu(relu(agg@r1+b)@r2+b) ----------------
__launch_bounds__(256, 3)
__global__ void layerB_k(const float* __restrict__ agg,
                         const short* __restrict__ r1Wt, const float* __restrict__ r1B,
                         const short* __restrict__ r2Wt, const float* __restrict__ r2B,
                         float* __restrict__ msg) {
    __shared__ short lds[64 * 128];
    const int tid = threadIdx.x;
    const int lane = tid & 63, w = tid >> 6;
    const size_t row0 = (size_t)blockIdx.x * 64;
    stage64x128(agg, row0, lds, tid);
    __syncthreads();
    const int kgrp = lane >> 4, ccol = lane & 15;
    const int arow = w * 16 + ccol;
    const int cr0  = w * 16 + kgrp * 4;
    short8 a1[4];
    #pragma unroll
    for (int kb = 0; kb < 4; ++kb)
        a1[kb] = *(const short8*)&lds[sidx(arow, kb * 64 + kgrp * 16)];
    floatx4 o[8];
    colmm8_pf<4, 128>(a1, r1Wt + ccol * 128 + kgrp * 8, o);
    #pragma unroll
    for (int c = 0; c < 8; ++c) {
        int colg = c * 16 + ccol;
        float b1 = r1B[colg];
        #pragma unroll
        for (int j = 0; j < 4; ++j)
            lds[sidx(cr0 + j, 2 * colg)] = f2bf(fmaxf(o[c][j] + b1, 0.f));
    }
    // wave-band-local: no barrier needed
    short8 a2[4];
    #pragma unroll
    for (int kb = 0; kb < 4; ++kb)
        a2[kb] = *(const short8*)&lds[sidx(arow, kb * 64 + kgrp * 16)];
    colmm8_pf<4, 128>(a2, r2Wt + ccol * 128 + kgrp * 8, o);
    #pragma unroll
    for (int c = 0; c < 8; ++c) {
        int colg = c * 16 + ccol;
        float b2 = r2B[colg];
        #pragma unroll
        for (int j = 0; j < 4; ++j) {
            size_t ofs = (row0 + cr0 + j) * 128 + colg;
            msg[ofs] = msg[ofs] + agg[ofs] + fmaxf(o[c][j] + b2, 0.f);
        }
    }
}

// ---------------- rbfe (bf16 out): relu(rbfh@W3 + b + P1[t(i)] + P2[t(j)]) ----------------
__launch_bounds__(256, 3)
__global__ void rbfe_k(const float* __restrict__ rbfh, const short* __restrict__ W3t,
                       const float* __restrict__ bias,
                       const int* __restrict__ idx_i, const int* __restrict__ idx_j,
                       const int* __restrict__ atype,
                       const float* __restrict__ P1, const float* __restrict__ P2,
                       short* __restrict__ out) {
    __shared__ short lds[64 * 128];
    const int tid = threadIdx.x;
    const int lane = tid & 63, w = tid >> 6;
    const size_t row0 = (size_t)blockIdx.x * 64;
    stage64x128(rbfh, row0, lds, tid);
    const int kgrp = lane >> 4, ccol = lane & 15;
    const int arow = w * 16 + ccol;
    const int cr0  = w * 16 + kgrp * 4;
    const float* p1p[4]; const float* p2p[4];
    #pragma unroll
    for (int j = 0; j < 4; ++j) {
        size_t row = row0 + cr0 + j;
        p1p[j] = P1 + (size_t)atype[idx_i[row]] * 128;
        p2p[j] = P2 + (size_t)atype[idx_j[row]] * 128;
    }
    __syncthreads();
    short8 a[4];
    #pragma unroll
    for (int kb = 0; kb < 4; ++kb)
        a[kb] = *(const short8*)&lds[sidx(arow, kb * 64 + kgrp * 16)];
    floatx4 o[8];
    colmm8_pf<4, 128>(a, W3t + ccol * 128 + kgrp * 8, o);
    #pragma unroll
    for (int c = 0; c < 8; ++c) {
        int colg = c * 16 + ccol;
        float bv = bias[colg];
        #pragma unroll
        for (int j = 0; j < 4; ++j)
            out[(row0 + cr0 + j) * 128 + colg] =
                f2bf(fmaxf(o[c][j] + bv + p1p[j][colg] + p2p[j][colg], 0.f));
    }
}

// ---------------- concat GEMM (fp32, final projection only) ----------------
template<bool GATHER>
__launch_bounds__(256)
__global__ void concatgemm_k(const float* __restrict__ IN1, int K1,
                             const float* __restrict__ IN2, int K2,
                             const int* __restrict__ gidx,
                             const float* __restrict__ W, const float* __restrict__ bias,
                             float* __restrict__ Y, int M) {
    __shared__ float xs[96 * 68];
    const int tid = threadIdx.x;
    const int row0 = blockIdx.x * 64;
    const int col8 = (tid & 15) * 8;
    const int r0 = (tid >> 4) * 4;
    const int K = K1 + K2;

    float acc[4][8];
    #pragma unroll
    for (int r = 0; r < 4; ++r)
        #pragma unroll
        for (int c = 0; c < 8; ++c) acc[r][c] = 0.f;

    for (int kb = 0; kb < K; kb += 96) {
        int kc = (K - kb < 96) ? (K - kb) : 96;
        __syncthreads();
        for (int idx = tid; idx < 64 * 96; idx += 256) {
            int r = idx / 96, kl = idx % 96;
            if (kl < kc) {
                int row = row0 + r;
                float v = 0.f;
                if (row < M) {
                    int kg = kb + kl;
                    if (kg < K1) {
                        int g = GATHER ? gidx[row] : row;
                        v = IN1[(size_t)g * K1 + kg];
                    } else {
                        v = IN2[(size_t)row * K2 + (kg - K1)];
                    }
                }
                xs[kl * 68 + r] = v;
            }
        }
        __syncthreads();
        for (int k = 0; k < kc; ++k) {
            float4 xv = *(const float4*)&xs[k * 68 + r0];
            const float* wr = &W[(size_t)(kb + k) * 128 + col8];
            float4 w0 = *(const float4*)wr;
            float4 w1 = *(const float4*)(wr + 4);
            float xr[4] = {xv.x, xv.y, xv.z, xv.w};
            float wc[8] = {w0.x, w0.y, w0.z, w0.w, w1.x, w1.y, w1.z, w1.w};
            #pragma unroll
            for (int r = 0; r < 4; ++r)
                #pragma unroll
                for (int c = 0; c < 8; ++c)
                    acc[r][c] = fmaf(xr[r], wc[c], acc[r][c]);
        }
    }

    float4 b0 = *(const float4*)&bias[col8];
    float4 b1 = *(const float4*)&bias[col8 + 4];
    float bb[8] = {b0.x, b0.y, b0.z, b0.w, b1.x, b1.y, b1.z, b1.w};
    #pragma unroll
    for (int r = 0; r < 4; ++r) {
        int row = row0 + r0 + r;
        if (row >= M) continue;
        float v[8];
        #pragma unroll
        for (int c = 0; c < 8; ++c) v[c] = fmaxf(acc[r][c] + bb[c], 0.f);
        *(float4*)&Y[(size_t)row * 128 + col8]     = make_float4(v[0], v[1], v[2], v[3]);
        *(float4*)&Y[(size_t)row * 128 + col8 + 4] = make_float4(v[4], v[5], v[6], v[7]);
    }
}

// ---------------- host ----------------

extern "C" void kernel_launch(void* const* d_in, const int* in_sizes, int n_in,
                              void* d_out, int out_size, void* d_ws, size_t ws_size,
                              hipStream_t stream) {
    const float* atom_feature = (const float*)d_in[0];
    const float* edge_feature = (const float*)d_in[1];
    const float* dist         = (const float*)d_in[2];
    const float* angle        = (const float*)d_in[3];
    const float* W_i1_w       = (const float*)d_in[4];
    const float* W_i1_b       = (const float*)d_in[5];
    const float* emb_table    = (const float*)d_in[6];
    const float* lin_rbf_w    = (const float*)d_in[7];
    const float* lin_rbf_b    = (const float*)d_in[8];
    const float* lin_emb_w    = (const float*)d_in[9];
    const float* lin_emb_b    = (const float*)d_in[10];
    const float* bessel_freq  = (const float*)d_in[11];
    const float* L_rbf2_w     = (const float*)d_in[12];
    const float* L_rbf2_b     = (const float*)d_in[13];
    const float* L_kj_w       = (const float*)d_in[14];
    const float* L_kj_b       = (const float*)d_in[15];
    const float* L_sbf1_w     = (const float*)d_in[16];
    const float* L_sbf2_w     = (const float*)d_in[17];
    const float* L_down_w     = (const float*)d_in[18];
    const float* L_down_b     = (const float*)d_in[19];
    const float* L_up_w       = (const float*)d_in[20];
    const float* L_up_b       = (const float*)d_in[21];
    const float* L_res1_w     = (const float*)d_in[22];
    const float* L_res1_b     = (const float*)d_in[23];
    const float* L_res2_w     = (const float*)d_in[24];
    const float* L_res2_b     = (const float*)d_in[25];
    const float* W_o_w        = (const float*)d_in[26];
    const float* W_o_b        = (const float*)d_in[27];
    const int* idx_i          = (const int*)d_in[28];
    const int* idx_j          = (const int*)d_in[29];
    const int* idx_kj         = (const int*)d_in[30];
    const int* ib_eid         = (const int*)d_in[32];
    const int* ib_atom        = (const int*)d_in[33];

    float* ws = (float*)d_ws;
    size_t off = 0;
    auto take = [&](size_t n) { float* p = ws + off; off += n; return p; };
    float* msg   = take((size_t)Ecnt * 128);
    short* rbfe  = (short*)take((size_t)Ecnt * 64);   // bf16 [E][128]
    float* agg   = take((size_t)Ecnt * 128);          // also rbf_h temp
    short* sxd   = (short*)take((size_t)Ecnt * 64);   // bf16 xdown (transposed layout)
    float* rbf0b = take((size_t)Ecnt * 16);
    float* atomm = take((size_t)Ncnt * 128);
    float* P1    = take(100 * 128);
    float* P2    = take(100 * 128);
    int*   atyp  = (int*)take(Ncnt);
    int*   cnts  = (int*)take(Ecnt);
    int*   basep = (int*)take(Ecnt);
    int*   cur   = (int*)take(Ecnt);
    int*   btot  = (int*)take(512);
    int*   boff  = (int*)take(512);
    int*   eids  = (int*)take(Tcnt);
    float* angs  = take(Tcnt);
    short* wts   = (short*)take(160000);   // 290816 shorts needed; 320000 given

    if (off * sizeof(float) > ws_size) {
        sentinel_k<<<1, 256, 0, stream>>>((float*)d_out, (float)ws_size);
        return;
    }

    const int GE  = Ecnt / 64;            // 1875 exact
    const int GN  = (Ncnt + 63) / 64;     // 235
    const int GT  = (Tcnt + 63) / 64;     // 7813
    const int NBE = (Ecnt + 255) / 256;
    const int NBT = (Tcnt + 255) / 256;

    // --- prep ---
    atype_k<<<(Ncnt + 255) / 256, 256, 0, stream>>>(atom_feature, atyp);
    pemb_k<<<100, 128, 0, stream>>>(emb_table, lin_emb_w, P1, P2);
    rbf0_k<<<NBE, 256, 0, stream>>>(dist, bessel_freq, rbf0b);

    hipMemsetAsync(cnts, 0, (size_t)Ecnt * sizeof(int), stream);
    hist_k<<<NBT, 256, 0, stream>>>(idx_kj, cnts);
    scan1_k<<<NBE, 256, 0, stream>>>(cnts, basep, btot);
    scan2_k<<<1, 512, 0, stream>>>(btot, boff, NBE);
    scan3_k<<<NBE, 256, 0, stream>>>(basep, boff, cur);
    perm_k<<<NBT, 256, 0, stream>>>(idx_kj, angle, cur, eids, angs);

    // --- bf16 transposed weights ---
    short* p = wts;
    short* wt1[2]; short* wt2[2]; short* wt3[2];
    short* wkj[2]; short* wr2f[2]; short* wdn[2]; short* wr1[2]; short* wr2[2];
    for (int l = 0; l < 2; ++l) {
        wt1[l] = p; p += 96 * 128;
        wt2[l] = p; p += 128 * 128;
        wt3[l] = p; p += 128 * 128;
        wkj[l] = p; p += 128 * 128;
        wr2f[l] = p; p += 128 * 128;
        wdn[l] = p; p += 128 * 128;
        wr1[l] = p; p += 128 * 128;
        wr2[l] = p; p += 128 * 128;
    }
    short* wemb3 = p; p += 128 * 128;
    short* wi1t  = p; p += 128 * 160;

    WPack wp;
    int m = 0;
    for (int l = 0; l < 2; ++l) {
        wp.src[m] = L_sbf2_w + (size_t)l * 128 * 128; wp.dst[m++] = wt2[l];
        wp.src[m] = L_up_w   + (size_t)l * 128 * 128; wp.dst[m++] = wt3[l];
        wp.src[m] = L_kj_w   + (size_t)l * 128 * 128; wp.dst[m++] = wkj[l];
        wp.src[m] = L_rbf2_w + (size_t)l * 128 * 128; wp.dst[m++] = wr2f[l];
        wp.src[m] = L_down_w + (size_t)l * 128 * 128; wp.dst[m++] = wdn[l];
        wp.src[m] = L_res1_w + (size_t)l * 128 * 128; wp.dst[m++] = wr1[l];
        wp.src[m] = L_res2_w + (size_t)l * 128 * 128; wp.dst[m++] = wr2[l];
    }
    wp.src[m] = lin_emb_w + 256 * 128; wp.dst[m++] = wemb3;   // m == 15
    transmany_k<<<15 * 64, 256, 0, stream>>>(wp);
    const int G96 = (96 * 128 + 255) / 256;
    transcvt_k<<<G96, 256, 0, stream>>>(L_sbf1_w, wt1[0], 96);
    transcvt_k<<<G96, 256, 0, stream>>>(L_sbf1_w + (size_t)96 * 128, wt1[1], 96);
    transWi1_k<<<(128 * 160 + 255) / 256, 256, 0, stream>>>(W_i1_w, wi1t);

    // --- initial message + rbf_e ---
    imsg_k<<<GE, 256, 0, stream>>>(atom_feature, edge_feature, idx_j, wi1t, W_i1_b, msg);
    rbfh_k<<<(Ecnt * 128) / 256, 256, 0, stream>>>(rbf0b, lin_rbf_w, lin_rbf_b, agg);
    rbfe_k<<<GE, 256, 0, stream>>>(agg, wemb3, lin_emb_b, idx_i, idx_j, atyp, P1, P2, rbfe);

    for (int l = 0; l < 2; ++l) {
        layerA_k<<<GE, 256, 0, stream>>>(msg, rbfe,
                                         wkj[l], L_kj_b + (size_t)l * 128,
                                         wr2f[l], L_rbf2_b + (size_t)l * 128,
                                         wdn[l], L_down_b + (size_t)l * 128, sxd);
        hipMemsetAsync(agg, 0, (size_t)Ecnt * 128 * sizeof(float), stream);
        triplet_mfma_k<<<GT, 256, 0, stream>>>(angs, eids, rbf0b,
                                               wt1[l], wt2[l], wt3[l],
                                               L_up_b + (size_t)l * 128, sxd, agg);
        layerB_k<<<GE, 256, 0, stream>>>(agg,
                                         wr1[l], L_res1_b + (size_t)l * 128,
                                         wr2[l], L_res2_b + (size_t)l * 128, msg);
    }

    // atom_message scatter + final projection
    hipMemsetAsync(atomm, 0, (size_t)Ncnt * 128 * sizeof(float), stream);
    scatatom_k<<<(Ecnt * 128) / 256, 256, 0, stream>>>(msg, ib_eid, ib_atom, atomm);
    concatgemm_k<false><<<GN, 256, 0, stream>>>(atom_feature, 133, atomm, 128,
                                                nullptr, W_o_w, W_o_b, (float*)d_out, Ncnt);
}